// Round 1
// 767.677 us; speedup vs baseline: 1.8178x; 1.8178x over previous
//
#include <hip/hip_runtime.h>
#include <hip/hip_bf16.h>

// Problem constants
#define C      128
#define SP     21952          // 28*28*28
#define PT     87808          // 4*SP
#define LW     343            // 7^3 window length
#define EPS_   1e-6f
#define SCALE_ 0.17677669529663687f  // 32^-0.5

// misc workspace layout (floats)
#define MISC_A   0
#define MISC_B   128
#define MISC_BQK 256
#define MISC_BV  512
#define MISC_SUM 640
#define MISC_SQ  768
#define MISC_A2  896
#define MISC_B2  1024

typedef __attribute__((ext_vector_type(8))) short bf16x8;
typedef __attribute__((ext_vector_type(4))) float f32x4;

__device__ __forceinline__ float b2f(unsigned short u){
  return __uint_as_float(((unsigned int)u) << 16);
}
__device__ __forceinline__ unsigned short f2b(float f){
  unsigned int u = __float_as_uint(f);
  u += 0x7fffu + ((u >> 16) & 1u);     // round-to-nearest-even
  return (unsigned short)(u >> 16);
}

// K0: per-channel mean/var of x -> folded scale a=rstd*g, shift b'=b-mean*a
__global__ void k0_stats(const float* __restrict__ x, const float* __restrict__ g,
                         const float* __restrict__ b, float* __restrict__ misc){
  int c = blockIdx.x;
  float s = 0.f, ss = 0.f;
  for (int bb = 0; bb < 4; ++bb){
    const float* p = x + (size_t)(bb*C + c) * SP;
    for (int i = threadIdx.x; i < SP; i += 256){
      float v = p[i]; s += v; ss += v*v;
    }
  }
  __shared__ float rs[256], rq[256];
  rs[threadIdx.x] = s; rq[threadIdx.x] = ss;
  __syncthreads();
  for (int off = 128; off > 0; off >>= 1){
    if (threadIdx.x < off){ rs[threadIdx.x] += rs[threadIdx.x+off]; rq[threadIdx.x] += rq[threadIdx.x+off]; }
    __syncthreads();
  }
  if (threadIdx.x == 0){
    float mean = rs[0] / (float)PT;
    float var  = rq[0] / (float)PT - mean*mean;
    float a = rsqrtf(var + EPS_) * g[c];
    misc[MISC_A + c] = a;
    misc[MISC_B + c] = b[c] - mean * a;
  }
}

// K1: fold BN shift through the 1x1 weights: bias_o = sum_c W[o,c]*bvec[c]
__global__ void k1_bias(const float* __restrict__ wqk, const float* __restrict__ wvv,
                        float* __restrict__ misc){
  int o = blockIdx.x*128 + threadIdx.x;   // grid 3 x 128 = 384
  const float* bv = misc + MISC_B;
  float acc = 0.f;
  if (o < 256){
    const float* wr = wqk + (size_t)o*128;
    for (int c = 0; c < 128; ++c) acc += wr[c]*bv[c];
    misc[MISC_BQK + o] = acc;
  } else {
    const float* wr = wvv + (size_t)(o-256)*128;
    for (int c = 0; c < 128; ++c) acc += wr[c]*bv[c];
    misc[MISC_BV + (o-256)] = acc;
  }
}

// K2: qkv projection GEMM. Output q,k,v bf16 in window layout [bw][h][l][32].
__global__ __launch_bounds__(256) void k2_qkv(const float* __restrict__ x,
        const float* __restrict__ wqk, const float* __restrict__ wvv,
        const float* __restrict__ misc,
        unsigned short* __restrict__ qg, unsigned short* __restrict__ kg,
        unsigned short* __restrict__ vg){
  __shared__ __align__(16) float xs[128*64];
  __shared__ __align__(16) float wsh[32*128];
  int t = threadIdx.x;
  int P0 = blockIdx.x * 64;
  int b = P0 / SP;
  int sp0 = P0 % SP;
  const float* xb = x + (size_t)b*C*SP + sp0;
  for (int idx = t; idx < 8192; idx += 256){
    int c = idx >> 6, p = idx & 63;
    xs[idx] = xb[(size_t)c*SP + p] * misc[MISC_A + c];
  }
  int p  = t & 63;
  int o0 = (t >> 6) * 8;
  // window decomposition (loop-invariant)
  int sp = sp0 + p;
  int h_ = sp / 784, rem = sp % 784;
  int w_ = rem / 28, d_ = rem % 28;
  int w1 = h_ & 3, s1 = h_ >> 2;
  int w2 = w_ & 3, s2 = w_ >> 2;
  int w3 = d_ & 3, s3 = d_ >> 2;
  int bw = ((b*4 + w1)*4 + w2)*4 + w3;
  int l  = (s1*7 + s2)*7 + s3;
  for (int oy = 0; oy < 12; ++oy){
    int obase = oy * 32;
    __syncthreads();   // xs ready (first iter) / prev compute done with wsh
    for (int idx = t; idx < 4096; idx += 256){
      int orow = idx >> 7, cc = idx & 127;
      int og = obase + orow;
      wsh[idx] = (og < 256) ? wqk[(size_t)og*128 + cc] : wvv[(size_t)(og-256)*128 + cc];
    }
    __syncthreads();
    float acc[8];
    #pragma unroll
    for (int j = 0; j < 8; ++j){
      int o = obase + o0 + j;
      acc[j] = (o < 256) ? misc[MISC_BQK + o] : misc[MISC_BV + (o - 256)];
    }
    const float4* w4p = reinterpret_cast<const float4*>(wsh);
    for (int cq = 0; cq < 32; ++cq){
      float x0 = xs[(cq*4+0)*64 + p];
      float x1 = xs[(cq*4+1)*64 + p];
      float x2 = xs[(cq*4+2)*64 + p];
      float x3 = xs[(cq*4+3)*64 + p];
      #pragma unroll
      for (int j = 0; j < 8; ++j){
        float4 wf = w4p[(o0+j)*32 + cq];
        acc[j] += wf.x*x0 + wf.y*x1 + wf.z*x2 + wf.w*x3;
      }
    }
    int oglob = obase + o0;
    bool isv = (oglob >= 256);
    unsigned int pk[4];
    #pragma unroll
    for (int jj = 0; jj < 4; ++jj){
      float lo = acc[2*jj], hi = acc[2*jj+1];
      if (isv){ lo = fmaxf(lo, 0.f); hi = fmaxf(hi, 0.f); }   // relu on v only
      pk[jj] = (unsigned int)f2b(lo) | ((unsigned int)f2b(hi) << 16);
    }
    int hh = (oglob >> 5) & 3;
    int dd0 = oglob & 31;
    unsigned short* dst = (oglob < 128) ? qg : (oglob < 256 ? kg : vg);
    size_t oidx = (((size_t)bw*4 + hh)*LW + l)*32 + dd0;
    *reinterpret_cast<uint4*>(dst + oidx) = make_uint4(pk[0], pk[1], pk[2], pk[3]);
  }
}

// K3 (MFMA rewrite): attention per (window, head) on mfma_f32_16x16x32_bf16.
// Layouts derived from the WORKING k4_mfma kernel in this file (ground truth):
//   A-frag: row = lane&15, k = (lane>>4)*8 + i   (8 contiguous bf16)
//   B-frag: col = lane&15, k = (lane>>4)*8 + i   (8 contiguous bf16)
//   D:      col = lane&15, row = (lane>>4)*4 + reg
// Per wave: one 16-row tile at a time (22 tiles round-robined over 4 waves).
//   QK^T: Q A-frag straight from global (16B/lane coalesced), K B-frags from
//   linear klds[352][32] (conflict-optimal b128). Row-max in regs (shfl<16).
//   Softmax deferred-normalize: unnormalized exp -> bf16 P via v_cvt_pk ->
//   per-wave LDS chunk buffer (stride 40: 2-way-free writes, optimal reads) ->
//   A-frag for PV. V staged transposed with the SAME 32-key interleave
//   permutation as P's k-order (dot product invariant), stride 360 so b128
//   reads are conflict-optimal. O scaled by 1/rowsum at the end.
// K/V pad rows (343..351) zeroed; tile-21 cols masked from max and exp.
// Wave-local LDS transpose hazard (per-lane write/read addrs differ -> compiler
// sees no dep): fenced with s_waitcnt lgkmcnt(0) + sched_barrier(0) (rule 18).
__global__ __launch_bounds__(256) void k3_attn(const unsigned short* __restrict__ qg,
        const unsigned short* __restrict__ kg, const unsigned short* __restrict__ vg,
        unsigned short* __restrict__ xatt){
  __shared__ __align__(16) unsigned short klds[352*32];    // [m][d]     22528 B
  __shared__ __align__(16) unsigned short vper[32*360];    // [d][m']    23040 B
  __shared__ __align__(16) unsigned short pbuf[4][640];    // per-wave [16][40]
  int bh = blockIdx.x;
  int bw = bh >> 2, h = bh & 3;
  int t = threadIdx.x;
  int wid = t >> 6, lane = t & 63;
  int g = lane >> 4, ln = lane & 15;
  const unsigned short* kbase = kg + (size_t)bh*LW*32;
  const unsigned short* vbase = vg + (size_t)bh*LW*32;
  const unsigned short* qbase = qg + (size_t)bh*LW*32;
  // stage K: straight uint4 copy, zero pad rows 343..351
  {
    const uint4* src = reinterpret_cast<const uint4*>(kbase);
    uint4* dst = reinterpret_cast<uint4*>(klds);
    for (int i = t; i < 1372; i += 256) dst[i] = src[i];
    for (int i = t; i < 288; i += 256) klds[10976 + i] = 0;
  }
  // stage V transposed + 32-key interleave: m -> (c = m>>5, pk = 2*(m&15) | ((m>>4)&1))
  for (int idx = t; idx < 10976; idx += 256){
    int m = idx >> 5, d = idx & 31;
    int km = m & 31;
    int pk = ((km & 15) << 1) | (km >> 4);
    vper[d*360 + ((m >> 5) << 5) + pk] = vbase[idx];
  }
  for (int i = t; i < 288; i += 256){       // zero V pad rows 343..351
    int m = 343 + (i >> 5), d = i & 31;
    int km = m & 31;
    int pk = ((km & 15) << 1) | (km >> 4);
    vper[d*360 + 320 + pk] = 0;
  }
  __syncthreads();
  int w1 = (bw>>4)&3, w2 = (bw>>2)&3, w3 = bw&3, b = bw>>6;
  unsigned short* pb = pbuf[wid];
  const f32x4 zero4 = {0.f, 0.f, 0.f, 0.f};
  for (int rt = wid; rt < 22; rt += 4){
    int row0 = rt << 4;
    // Q A-frag direct from global: 16B per lane, rows row0+ln (pad rows read
    // garbage inside workspace; NaN stays confined to its own output row,
    // which is never stored).
    bf16x8 qf = *reinterpret_cast<const bf16x8*>(qbase + (size_t)(row0 + ln)*32 + g*8);
    // QK^T: 22 n-tiles, single k-step (K=32=DH)
    f32x4 s[22];
    #pragma unroll
    for (int nt = 0; nt < 22; ++nt){
      bf16x8 kf = *reinterpret_cast<const bf16x8*>(&klds[(nt*16 + ln)*32 + g*8]);
      s[nt] = __builtin_amdgcn_mfma_f32_16x16x32_bf16(qf, kf, zero4, 0, 0, 0);
    }
    // per-row max (row = g*4+q lives in reg q across the 16 lanes of group g)
    float mxs[4];
    #pragma unroll
    for (int q = 0; q < 4; ++q){
      float m0 = -1e30f;
      #pragma unroll
      for (int nt = 0; nt < 21; ++nt) m0 = fmaxf(m0, s[nt][q]);
      if (ln < 7) m0 = fmaxf(m0, s[21][q]);     // tile 21 valid only for cols 336..342
      #pragma unroll
      for (int off = 8; off > 0; off >>= 1) m0 = fmaxf(m0, __shfl_xor(m0, off));
      mxs[q] = m0 * SCALE_;
    }
    f32x4 o0 = zero4, o1 = zero4;
    float sums[4] = {0.f, 0.f, 0.f, 0.f};
    #pragma unroll
    for (int c = 0; c < 11; ++c){
      // exp (unnormalized, <=1) -> packed bf16 -> per-wave LDS chunk [16][40]
      #pragma unroll
      for (int q = 0; q < 4; ++q){
        float e0 = __expf(fmaf(s[2*c][q],   SCALE_, -mxs[q]));          // cols c*32+ln    <= 335: always valid
        float e1 = (c*32 + 16 + ln < 343)
                 ? __expf(fmaf(s[2*c+1][q], SCALE_, -mxs[q])) : 0.f;    // mask cols >= 343 (folds for c<=9)
        sums[q] += e0 + e1;
        unsigned int pkd;
        asm volatile("v_cvt_pk_bf16_f32 %0, %1, %2" : "=v"(pkd) : "v"(e0), "v"(e1));
        *reinterpret_cast<unsigned int*>(&pb[(g*4+q)*40 + (ln<<1)]) = pkd;
      }
      // fence the wave-local LDS transpose (per-lane addrs differ; compiler
      // would otherwise see no dependency between the writes and the read)
      asm volatile("s_waitcnt lgkmcnt(0)" ::: "memory");
      __builtin_amdgcn_sched_barrier(0);
      bf16x8 pa  = *reinterpret_cast<const bf16x8*>(&pb[ln*40 + g*8]);
      bf16x8 vb0 = *reinterpret_cast<const bf16x8*>(&vper[ln*360       + (c<<5) + g*8]);
      bf16x8 vb1 = *reinterpret_cast<const bf16x8*>(&vper[(16+ln)*360  + (c<<5) + g*8]);
      o0 = __builtin_amdgcn_mfma_f32_16x16x32_bf16(pa, vb0, o0, 0, 0, 0);
      o1 = __builtin_amdgcn_mfma_f32_16x16x32_bf16(pa, vb1, o1, 0, 0, 0);
    }
    // normalize + scatter-store (same spatial mapping as before)
    float iss[4];
    #pragma unroll
    for (int q = 0; q < 4; ++q){
      float sq = sums[q];
      #pragma unroll
      for (int off = 8; off > 0; off >>= 1) sq += __shfl_xor(sq, off);
      iss[q] = 1.f / sq;
    }
    #pragma unroll
    for (int q = 0; q < 4; ++q){
      int l = row0 + g*4 + q;
      if (l < 343){
        int ss1 = l/49, ss2 = (l/7)%7, ss3 = l%7;
        int sp = (ss1*4+w1)*784 + (ss2*4+w2)*28 + (ss3*4+w3);
        size_t gaddr = ((size_t)b*SP + sp)*128 + h*32;
        xatt[gaddr + ln]      = f2b(o0[q]*iss[q]);
        xatt[gaddr + 16 + ln] = f2b(o1[q]*iss[q]);
      }
    }
  }
}

// K_wprep: w_cl [oc][ic][27] fp32 -> wbf bf16 slices [h][tap][kg][oc][8]
__global__ void k_wprep(const float* __restrict__ wcl, unsigned short* __restrict__ wbf){
  int f = blockIdx.x*256 + threadIdx.x;      // 442368 total
  int j  = f & 7;
  int oc = (f >> 3) & 127;
  int kgr= (f >> 10) & 7;
  int sl = f >> 13;                          // 0..53
  int h  = sl / 27, tap = sl % 27;
  int ic = h*64 + kgr*8 + j;
  wbf[f] = f2b(wcl[((size_t)oc*128 + ic)*27 + tap]);
}

// K4: 3x3x3 conv as implicit GEMM on mfma_f32_16x16x32_bf16.
__global__ __launch_bounds__(256) void k4_mfma(const unsigned short* __restrict__ xag,
        const unsigned short* __restrict__ wbf, unsigned short* __restrict__ yg){
  __shared__ __align__(16) unsigned short halo[8*216*8];   // 27648 B
  __shared__ __align__(16) unsigned short wt[2][8192];     // 2 x 16384 B
  int t = threadIdx.x, wid = t >> 6, lane = t & 63;
  int stile = blockIdx.x;
  int b = stile / 343, srem = stile % 343;
  int z0 = (srem/49)*4, y0 = ((srem/7)%7)*4, x0 = (srem%7)*4;
  int mhalf = wid & 1, ohalf = wid >> 1;
  int nn = lane & 15, quad = lane >> 4;
  int mA = mhalf*32 + nn;          // m-tile 0 row of this lane
  int mB = mA + 16;                // m-tile 1 row
  int hp0 = (mA>>4)*36 + ((mA>>2)&3)*6 + (mA&3);
  int hp1 = (mB>>4)*36 + ((mB>>2)&3)*6 + (mB&3);
  f32x4 acc[2][4] = {};

  #define WLOAD(s_, buf_) do { \
    const unsigned short* gs = wbf + (size_t)(s_)*8192 + (size_t)(wid*4*64 + lane)*8; \
    _Pragma("unroll") \
    for (int it = 0; it < 4; ++it){ \
      __builtin_amdgcn_global_load_lds( \
        (const __attribute__((address_space(1))) unsigned int*)(gs + it*512), \
        (__attribute__((address_space(3))) unsigned int*)(&wt[buf_][(wid*4+it)*512]), \
        16, 0, 0); \
    } \
  } while(0)

  int s = 0;
  WLOAD(0, 0);
  for (int h = 0; h < 2; ++h){
    for (int cidx = t; cidx < 1728; cidx += 256){
      int kgr = cidx / 216, pos = cidx % 216;
      int uz = pos / 36, r36 = pos % 36, uy = r36 / 6, ux = r36 % 6;
      int zz = z0 - 1 + uz, yy = y0 - 1 + uy, xx = x0 - 1 + ux;
      uint4 v = make_uint4(0u,0u,0u,0u);
      if (zz >= 0 && zz < 28 && yy >= 0 && yy < 28 && xx >= 0 && xx < 28)
        v = *reinterpret_cast<const uint4*>(
              &xag[(((size_t)b*SP) + zz*784 + yy*28 + xx)*128 + h*64 + kgr*8]);
      *reinterpret_cast<uint4*>(&halo[(size_t)cidx*8]) = v;
    }
    __syncthreads();
    for (int tap = 0; tap < 27; ++tap){
      if (s + 1 < 54) WLOAD(s + 1, (s + 1) & 1);
      const unsigned short* wc = wt[s & 1];
      int dz = tap / 9, r9 = tap % 9, dy = r9 / 3, dx = r9 % 3;
      int off = dz*36 + dy*6 + dx;
      #pragma unroll
      for (int ks = 0; ks < 2; ++ks){
        int ksel = ks*4 + quad;
        bf16x8 a0 = *reinterpret_cast<const bf16x8*>(&halo[(ksel*216 + hp0 + off)*8]);
        bf16x8 a1 = *reinterpret_cast<const bf16x8*>(&halo[(ksel*216 + hp1 + off)*8]);
        #pragma unroll
        for (int nt = 0; nt < 4; ++nt){
          bf16x8 bb = *reinterpret_cast<const bf16x8*>(&wc[(ksel*128 + ohalf*64 + nt*16 + nn)*8]);
          acc[0][nt] = __builtin_amdgcn_mfma_f32_16x16x32_bf16(a0, bb, acc[0][nt], 0, 0, 0);
          acc[1][nt] = __builtin_amdgcn_mfma_f32_16x16x32_bf16(a1, bb, acc[1][nt], 0, 0, 0);
        }
      }
      ++s;
      __syncthreads();
    }
  }
  #pragma unroll
  for (int mt = 0; mt < 2; ++mt){
    #pragma unroll
    for (int nt = 0; nt < 4; ++nt){
      #pragma unroll
      for (int r = 0; r < 4; ++r){
        int m = mhalf*32 + mt*16 + quad*4 + r;
        int oc = ohalf*64 + nt*16 + nn;
        int pos = (z0 + (m>>4))*784 + (y0 + ((m>>2)&3))*28 + (x0 + (m&3));
        yg[((size_t)b*SP + pos)*128 + oc] = f2b(acc[mt][nt][r]);
      }
    }
  }
  #undef WLOAD
}

// K5: per-channel sum/sumsq of y via lane-private channel partials + atomics
__global__ void k5_ystats(const unsigned short* __restrict__ yg, float* __restrict__ misc){
  int t = threadIdx.x;
  float s = 0.f, ss = 0.f;
  size_t base = (size_t)blockIdx.x * 32768 + t;
  for (int k = 0; k < 128; ++k){
    float v = b2f(yg[base + (size_t)k*256]);
    s += v; ss += v*v;
  }
  __shared__ float rs[256], rq[256];
  rs[t] = s; rq[t] = ss;
  __syncthreads();
  if (t < 128){
    atomicAdd(&misc[MISC_SUM + t], rs[t] + rs[t+128]);
    atomicAdd(&misc[MISC_SQ  + t], rq[t] + rq[t+128]);
  }
}

__global__ void k5b_finstats(const float* __restrict__ gcl, const float* __restrict__ bcl,
                             float* __restrict__ misc){
  int c = threadIdx.x;
  float mean = misc[MISC_SUM+c] / (float)PT;
  float var  = misc[MISC_SQ +c] / (float)PT - mean*mean;
  float a = gcl[c] * rsqrtf(var + EPS_);
  misc[MISC_A2+c] = a;
  misc[MISC_B2+c] = bcl[c] - mean*a;
}

// K6: out = shortcut + Wproj @ (x_att + silu(bn(y)))
__global__ __launch_bounds__(256) void k6_final(const unsigned short* __restrict__ xag,
        const unsigned short* __restrict__ yg, const float* __restrict__ wproj,
        const float* __restrict__ xin, const float* __restrict__ misc,
        float* __restrict__ out){
  __shared__ __align__(16) float tls[128*65];   // [c][p] pad 65
  __shared__ __align__(16) float wls[32*128];
  int t = threadIdx.x;
  int P0 = blockIdx.x * 64;
  int b = P0 / SP, sp0 = P0 % SP;
  for (int idx = t; idx < 8192; idx += 256){
    int c = idx & 127, p = idx >> 7;
    size_t g = (size_t)(P0 + p)*128 + c;
    float yv = b2f(yg[g]) * misc[MISC_A2+c] + misc[MISC_B2+c];
    float sil = yv / (1.f + __expf(-yv));
    tls[c*65 + p] = b2f(xag[g]) + sil;
  }
  int p = t & 63, og = t >> 6;
  for (int qtr = 0; qtr < 4; ++qtr){
    __syncthreads();
    for (int idx = t; idx < 4096; idx += 256)
      wls[idx] = wproj[qtr*4096 + idx];
    __syncthreads();
    float acc[8];
    #pragma unroll
    for (int j = 0; j < 8; ++j) acc[j] = 0.f;
    const float4* w4p = reinterpret_cast<const float4*>(wls);
    for (int cq = 0; cq < 32; ++cq){
      float x0 = tls[(cq*4+0)*65 + p];
      float x1 = tls[(cq*4+1)*65 + p];
      float x2 = tls[(cq*4+2)*65 + p];
      float x3 = tls[(cq*4+3)*65 + p];
      #pragma unroll
      for (int j = 0; j < 8; ++j){
        float4 wf = w4p[(og*8+j)*32 + cq];
        acc[j] += wf.x*x0 + wf.y*x1 + wf.z*x2 + wf.w*x3;
      }
    }
    #pragma unroll
    for (int j = 0; j < 8; ++j){
      int o = qtr*32 + og*8 + j;
      size_t gaddr = ((size_t)b*128 + o)*SP + sp0 + p;
      out[gaddr] = xin[gaddr] + acc[j];
    }
  }
}

extern "C" void kernel_launch(void* const* d_in, const int* in_sizes, int n_in,
                              void* d_out, int out_size, void* d_ws, size_t ws_size,
                              hipStream_t stream){
  const float* x      = (const float*)d_in[0];
  const float* g_in   = (const float*)d_in[1];
  const float* b_in   = (const float*)d_in[2];
  const float* w_qk   = (const float*)d_in[3];
  const float* w_v    = (const float*)d_in[4];
  const float* w_cl   = (const float*)d_in[5];
  const float* g_cl   = (const float*)d_in[6];
  const float* b_cl   = (const float*)d_in[7];
  const float* w_proj = (const float*)d_in[8];
  float* out = (float*)d_out;

  char* ws = (char*)d_ws;
  unsigned short* qg  = (unsigned short*)ws;
  unsigned short* kgp = qg  + 11239424;
  unsigned short* vg  = kgp + 11239424;
  unsigned short* xag = vg  + 11239424;
  unsigned short* yg  = xag + 11239424;
  float* misc = (float*)(ws + (size_t)5*22478848);   // 112,394,240 B offset
  unsigned short* wbf = qg;   // reuses qg region AFTER k3 consumed q

  hipMemsetAsync(misc + MISC_SUM, 0, 256*sizeof(float), stream);
  k0_stats    <<<128, 256, 0, stream>>>(x, g_in, b_in, misc);
  k1_bias     <<<3, 128, 0, stream>>>(w_qk, w_v, misc);
  k2_qkv      <<<1372, 256, 0, stream>>>(x, w_qk, w_v, misc, qg, kgp, vg);
  k3_attn     <<<1024, 256, 0, stream>>>(qg, kgp, vg, xag);
  k_wprep     <<<1728, 256, 0, stream>>>(w_cl, wbf);
  k4_mfma     <<<1372, 256, 0, stream>>>(xag, wbf, yg);
  k5_ystats   <<<343, 256, 0, stream>>>(yg, misc);
  k5b_finstats<<<1, 128, 0, stream>>>(g_cl, b_cl, misc);
  k6_final    <<<1372, 256, 0, stream>>>(xag, yg, w_proj, x, misc, out);
}

// Round 2
// 597.242 us; speedup vs baseline: 2.3366x; 1.2854x over previous
//
#include <hip/hip_runtime.h>
#include <hip/hip_bf16.h>

// Problem constants
#define C      128
#define SP     21952          // 28*28*28
#define PT     87808          // 4*SP
#define LW     343            // 7^3 window length
#define EPS_   1e-6f
#define SCALE_ 0.17677669529663687f  // 32^-0.5

// misc workspace layout (floats)
#define MISC_A   0
#define MISC_B   128
#define MISC_BQK 256
#define MISC_BV  512
#define MISC_SUM 640
#define MISC_SQ  768
#define MISC_A2  896
#define MISC_B2  1024

typedef __attribute__((ext_vector_type(8))) short bf16x8;
typedef __attribute__((ext_vector_type(4))) float f32x4;

__device__ __forceinline__ float b2f(unsigned short u){
  return __uint_as_float(((unsigned int)u) << 16);
}
__device__ __forceinline__ unsigned short f2b(float f){
  unsigned int u = __float_as_uint(f);
  u += 0x7fffu + ((u >> 16) & 1u);     // round-to-nearest-even
  return (unsigned short)(u >> 16);
}

// K0: per-channel mean/var of x -> folded scale a=rstd*g, shift b'=b-mean*a
__global__ void k0_stats(const float* __restrict__ x, const float* __restrict__ g,
                         const float* __restrict__ b, float* __restrict__ misc){
  int c = blockIdx.x;
  float s = 0.f, ss = 0.f;
  for (int bb = 0; bb < 4; ++bb){
    const float* p = x + (size_t)(bb*C + c) * SP;
    for (int i = threadIdx.x; i < SP; i += 256){
      float v = p[i]; s += v; ss += v*v;
    }
  }
  __shared__ float rs[256], rq[256];
  rs[threadIdx.x] = s; rq[threadIdx.x] = ss;
  __syncthreads();
  for (int off = 128; off > 0; off >>= 1){
    if (threadIdx.x < off){ rs[threadIdx.x] += rs[threadIdx.x+off]; rq[threadIdx.x] += rq[threadIdx.x+off]; }
    __syncthreads();
  }
  if (threadIdx.x == 0){
    float mean = rs[0] / (float)PT;
    float var  = rq[0] / (float)PT - mean*mean;
    float a = rsqrtf(var + EPS_) * g[c];
    misc[MISC_A + c] = a;
    misc[MISC_B + c] = b[c] - mean * a;
  }
}

// K1: fold BN shift through the 1x1 weights: bias_o = sum_c W[o,c]*bvec[c]
__global__ void k1_bias(const float* __restrict__ wqk, const float* __restrict__ wvv,
                        float* __restrict__ misc){
  int o = blockIdx.x*128 + threadIdx.x;   // grid 3 x 128 = 384
  const float* bv = misc + MISC_B;
  float acc = 0.f;
  if (o < 256){
    const float* wr = wqk + (size_t)o*128;
    for (int c = 0; c < 128; ++c) acc += wr[c]*bv[c];
    misc[MISC_BQK + o] = acc;
  } else {
    const float* wr = wvv + (size_t)(o-256)*128;
    for (int c = 0; c < 128; ++c) acc += wr[c]*bv[c];
    misc[MISC_BV + (o-256)] = acc;
  }
}

// K1w: split qkv weights into bf16 hi/lo pairs: w2[0..49152) = hi, [49152..) = lo
__global__ void k1w(const float* __restrict__ wqk, const float* __restrict__ wvv,
                    unsigned short* __restrict__ w2){
  int idx = blockIdx.x*256 + threadIdx.x;   // 49152 total
  int o = idx >> 7;
  float w = (o < 256) ? wqk[idx] : wvv[idx - 32768];
  unsigned short h = f2b(w);
  w2[idx] = h;
  w2[49152 + idx] = f2b(w - b2f(h));
}

// K2 (MFMA rewrite): qkv projection on mfma_f32_16x16x32_bf16 with split-bf16
// fp32 emulation: out = xh*wh + xl*wh + xh*wl (missing xl*wl ~ 2^-18 relative).
//   A-frag (x): row = position (lane&15), k = channel ((lane>>4)*8+i), from
//     LDS [64][128] bf16, XOR-swizzled byte^=((row&7)<<4) -> b128 reads at the
//     8-cycle minimum (unswizzled 256B-stride rows are a 16-way conflict).
//   B-frag (W): col = out (lane&15), same k, straight from global (197KB hot
//     in L2 across all 1372 blocks).
//   D: col = out, row = position((lane>>4)*4+reg). Bias folded into acc init
//     (misc[256+o] is contiguous across the BQK/BV boundary). Relu on v tiles.
// Per wave: 6 n-tiles (96 outs) x 4 m-tiles x 4 k-steps x 3 passes = 288 MFMA.
__global__ __launch_bounds__(256) void k2_qkv(const float* __restrict__ x,
        const unsigned short* __restrict__ w2, const float* __restrict__ misc,
        unsigned short* __restrict__ qg, unsigned short* __restrict__ kg,
        unsigned short* __restrict__ vg){
  __shared__ __align__(16) unsigned short xh[8192];   // 16KB
  __shared__ __align__(16) unsigned short xl[8192];   // 16KB
  __shared__ float ascale[128];
  __shared__ unsigned int posTab[64];
  int t = threadIdx.x;
  int P0 = blockIdx.x * 64;
  int b = P0 / SP, sp0 = P0 % SP;
  if (t < 128) ascale[t] = misc[MISC_A + t];
  if (t < 64){
    int sp = sp0 + t;
    int h_ = sp / 784, rem = sp % 784;
    int w_ = rem / 28, d_ = rem % 28;
    int w1 = h_ & 3, s1 = h_ >> 2;
    int w2i = w_ & 3, s2 = w_ >> 2;
    int w3 = d_ & 3, s3 = d_ >> 2;
    int bw = ((b*4 + w1)*4 + w2i)*4 + w3;
    int l  = (s1*7 + s2)*7 + s3;
    posTab[t] = (unsigned int)(bw*43904 + l*32);   // ushort offset, +h*10976+d at store
  }
  __syncthreads();
  // stage x -> bf16 hi/lo (BN scale folded), swizzled
  {
    int p = t & 63;
    int ob = t >> 6;
    const float* xb = x + (size_t)b*C*SP + sp0 + p;
    for (int it = 0; it < 4; ++it){
      int c0 = (ob + it*4) * 8;
      unsigned int ph[4], pl[4];
      #pragma unroll
      for (int j = 0; j < 4; ++j){
        float f0 = xb[(size_t)(c0 + 2*j)*SP]     * ascale[c0 + 2*j];
        float f1 = xb[(size_t)(c0 + 2*j + 1)*SP] * ascale[c0 + 2*j + 1];
        unsigned short h0 = f2b(f0), h1 = f2b(f1);
        unsigned short l0 = f2b(f0 - b2f(h0)), l1 = f2b(f1 - b2f(h1));
        ph[j] = (unsigned int)h0 | ((unsigned int)h1 << 16);
        pl[j] = (unsigned int)l0 | ((unsigned int)l1 << 16);
      }
      int byte = (p*256 + c0*2) ^ ((p & 7) << 4);
      *reinterpret_cast<uint4*>((char*)xh + byte) = make_uint4(ph[0],ph[1],ph[2],ph[3]);
      *reinterpret_cast<uint4*>((char*)xl + byte) = make_uint4(pl[0],pl[1],pl[2],pl[3]);
    }
  }
  __syncthreads();
  int wid = t >> 6, lane = t & 63;
  int g = lane >> 4, ln = lane & 15;
  int wstart = wid * 96;
  f32x4 acc[6][4];
  #pragma unroll
  for (int nt = 0; nt < 6; ++nt){
    float bv = misc[256 + wstart + nt*16 + ln];
    #pragma unroll
    for (int mt = 0; mt < 4; ++mt) acc[nt][mt] = (f32x4){bv,bv,bv,bv};
  }
  #pragma unroll 1
  for (int kk = 0; kk < 4; ++kk){
    bf16x8 ah[4], al[4];
    #pragma unroll
    for (int mt = 0; mt < 4; ++mt){
      int row = mt*16 + ln;
      int byte = (row*256 + kk*64 + g*16) ^ ((ln & 7) << 4);
      ah[mt] = *reinterpret_cast<const bf16x8*>((const char*)xh + byte);
      al[mt] = *reinterpret_cast<const bf16x8*>((const char*)xl + byte);
    }
    #pragma unroll
    for (int nt = 0; nt < 6; ++nt){
      int o = wstart + nt*16 + ln;
      const unsigned short* wp = w2 + (size_t)o*128 + kk*32 + g*8;
      bf16x8 whf = *reinterpret_cast<const bf16x8*>(wp);
      bf16x8 wlf = *reinterpret_cast<const bf16x8*>(wp + 49152);
      #pragma unroll
      for (int mt = 0; mt < 4; ++mt){
        acc[nt][mt] = __builtin_amdgcn_mfma_f32_16x16x32_bf16(ah[mt], whf, acc[nt][mt], 0, 0, 0);
        acc[nt][mt] = __builtin_amdgcn_mfma_f32_16x16x32_bf16(al[mt], whf, acc[nt][mt], 0, 0, 0);
        acc[nt][mt] = __builtin_amdgcn_mfma_f32_16x16x32_bf16(ah[mt], wlf, acc[nt][mt], 0, 0, 0);
      }
    }
  }
  // epilogue: relu on v, bf16, scatter (16 consecutive lanes = 32B contiguous)
  unsigned int ptab[16];
  #pragma unroll
  for (int mt = 0; mt < 4; ++mt)
    #pragma unroll
    for (int r = 0; r < 4; ++r)
      ptab[mt*4+r] = posTab[mt*16 + g*4 + r];
  #pragma unroll
  for (int nt = 0; nt < 6; ++nt){
    int o = wstart + nt*16 + ln;
    bool isv = (o >= 256);
    int oo = o & 127;
    unsigned short* dst = ((o < 128) ? qg : (o < 256 ? kg : vg)) + (oo >> 5)*10976 + (oo & 31);
    #pragma unroll
    for (int mt = 0; mt < 4; ++mt){
      #pragma unroll
      for (int r = 0; r < 4; ++r){
        float v = acc[nt][mt][r];
        if (isv) v = fmaxf(v, 0.f);
        dst[ptab[mt*4+r]] = f2b(v);
      }
    }
  }
}

// K3 (MFMA): attention per (window, head) on mfma_f32_16x16x32_bf16.
__global__ __launch_bounds__(256) void k3_attn(const unsigned short* __restrict__ qg,
        const unsigned short* __restrict__ kg, const unsigned short* __restrict__ vg,
        unsigned short* __restrict__ xatt){
  __shared__ __align__(16) unsigned short klds[352*32];    // [m][d]     22528 B
  __shared__ __align__(16) unsigned short vper[32*360];    // [d][m']    23040 B
  __shared__ __align__(16) unsigned short pbuf[4][640];    // per-wave [16][40]
  int bh = blockIdx.x;
  int bw = bh >> 2, h = bh & 3;
  int t = threadIdx.x;
  int wid = t >> 6, lane = t & 63;
  int g = lane >> 4, ln = lane & 15;
  const unsigned short* kbase = kg + (size_t)bh*LW*32;
  const unsigned short* vbase = vg + (size_t)bh*LW*32;
  const unsigned short* qbase = qg + (size_t)bh*LW*32;
  // stage K: straight uint4 copy, zero pad rows 343..351
  {
    const uint4* src = reinterpret_cast<const uint4*>(kbase);
    uint4* dst = reinterpret_cast<uint4*>(klds);
    for (int i = t; i < 1372; i += 256) dst[i] = src[i];
    for (int i = t; i < 288; i += 256) klds[10976 + i] = 0;
  }
  // stage V transposed + 32-key interleave: m -> (c = m>>5, pk = 2*(m&15) | ((m>>4)&1))
  for (int idx = t; idx < 10976; idx += 256){
    int m = idx >> 5, d = idx & 31;
    int km = m & 31;
    int pk = ((km & 15) << 1) | (km >> 4);
    vper[d*360 + ((m >> 5) << 5) + pk] = vbase[idx];
  }
  for (int i = t; i < 288; i += 256){       // zero V pad rows 343..351
    int m = 343 + (i >> 5), d = i & 31;
    int km = m & 31;
    int pk = ((km & 15) << 1) | (km >> 4);
    vper[d*360 + 320 + pk] = 0;
  }
  __syncthreads();
  int w1 = (bw>>4)&3, w2 = (bw>>2)&3, w3 = bw&3, b = bw>>6;
  unsigned short* pb = pbuf[wid];
  const f32x4 zero4 = {0.f, 0.f, 0.f, 0.f};
  for (int rt = wid; rt < 22; rt += 4){
    int row0 = rt << 4;
    bf16x8 qf = *reinterpret_cast<const bf16x8*>(qbase + (size_t)(row0 + ln)*32 + g*8);
    // QK^T: 22 n-tiles, single k-step (K=32=DH)
    f32x4 s[22];
    #pragma unroll
    for (int nt = 0; nt < 22; ++nt){
      bf16x8 kf = *reinterpret_cast<const bf16x8*>(&klds[(nt*16 + ln)*32 + g*8]);
      s[nt] = __builtin_amdgcn_mfma_f32_16x16x32_bf16(qf, kf, zero4, 0, 0, 0);
    }
    float mxs[4];
    #pragma unroll
    for (int q = 0; q < 4; ++q){
      float m0 = -1e30f;
      #pragma unroll
      for (int nt = 0; nt < 21; ++nt) m0 = fmaxf(m0, s[nt][q]);
      if (ln < 7) m0 = fmaxf(m0, s[21][q]);
      #pragma unroll
      for (int off = 8; off > 0; off >>= 1) m0 = fmaxf(m0, __shfl_xor(m0, off));
      mxs[q] = m0 * SCALE_;
    }
    f32x4 o0 = zero4, o1 = zero4;
    float sums[4] = {0.f, 0.f, 0.f, 0.f};
    #pragma unroll
    for (int c = 0; c < 11; ++c){
      #pragma unroll
      for (int q = 0; q < 4; ++q){
        float e0 = __expf(fmaf(s[2*c][q],   SCALE_, -mxs[q]));
        float e1 = (c*32 + 16 + ln < 343)
                 ? __expf(fmaf(s[2*c+1][q], SCALE_, -mxs[q])) : 0.f;
        sums[q] += e0 + e1;
        unsigned int pkd;
        asm volatile("v_cvt_pk_bf16_f32 %0, %1, %2" : "=v"(pkd) : "v"(e0), "v"(e1));
        *reinterpret_cast<unsigned int*>(&pb[(g*4+q)*40 + (ln<<1)]) = pkd;
      }
      asm volatile("s_waitcnt lgkmcnt(0)" ::: "memory");
      __builtin_amdgcn_sched_barrier(0);
      bf16x8 pa  = *reinterpret_cast<const bf16x8*>(&pb[ln*40 + g*8]);
      bf16x8 vb0 = *reinterpret_cast<const bf16x8*>(&vper[ln*360       + (c<<5) + g*8]);
      bf16x8 vb1 = *reinterpret_cast<const bf16x8*>(&vper[(16+ln)*360  + (c<<5) + g*8]);
      o0 = __builtin_amdgcn_mfma_f32_16x16x32_bf16(pa, vb0, o0, 0, 0, 0);
      o1 = __builtin_amdgcn_mfma_f32_16x16x32_bf16(pa, vb1, o1, 0, 0, 0);
    }
    float iss[4];
    #pragma unroll
    for (int q = 0; q < 4; ++q){
      float sq = sums[q];
      #pragma unroll
      for (int off = 8; off > 0; off >>= 1) sq += __shfl_xor(sq, off);
      iss[q] = 1.f / sq;
    }
    #pragma unroll
    for (int q = 0; q < 4; ++q){
      int l = row0 + g*4 + q;
      if (l < 343){
        int ss1 = l/49, ss2 = (l/7)%7, ss3 = l%7;
        int sp = (ss1*4+w1)*784 + (ss2*4+w2)*28 + (ss3*4+w3);
        size_t gaddr = ((size_t)b*SP + sp)*128 + h*32;
        xatt[gaddr + ln]      = f2b(o0[q]*iss[q]);
        xatt[gaddr + 16 + ln] = f2b(o1[q]*iss[q]);
      }
    }
  }
}

// K_wprep: w_cl [oc][ic][27] fp32 -> wbf bf16 slices [h][tap][kg][oc][8]
__global__ void k_wprep(const float* __restrict__ wcl, unsigned short* __restrict__ wbf){
  int f = blockIdx.x*256 + threadIdx.x;      // 442368 total
  int j  = f & 7;
  int oc = (f >> 3) & 127;
  int kgr= (f >> 10) & 7;
  int sl = f >> 13;                          // 0..53
  int h  = sl / 27, tap = sl % 27;
  int ic = h*64 + kgr*8 + j;
  wbf[f] = f2b(wcl[((size_t)oc*128 + ic)*27 + tap]);
}

// K4: 3x3x3 conv as implicit GEMM on mfma_f32_16x16x32_bf16.
__global__ __launch_bounds__(256) void k4_mfma(const unsigned short* __restrict__ xag,
        const unsigned short* __restrict__ wbf, unsigned short* __restrict__ yg){
  __shared__ __align__(16) unsigned short halo[8*216*8];   // 27648 B
  __shared__ __align__(16) unsigned short wt[2][8192];     // 2 x 16384 B
  int t = threadIdx.x, wid = t >> 6, lane = t & 63;
  int stile = blockIdx.x;
  int b = stile / 343, srem = stile % 343;
  int z0 = (srem/49)*4, y0 = ((srem/7)%7)*4, x0 = (srem%7)*4;
  int mhalf = wid & 1, ohalf = wid >> 1;
  int nn = lane & 15, quad = lane >> 4;
  int mA = mhalf*32 + nn;          // m-tile 0 row of this lane
  int mB = mA + 16;                // m-tile 1 row
  int hp0 = (mA>>4)*36 + ((mA>>2)&3)*6 + (mA&3);
  int hp1 = (mB>>4)*36 + ((mB>>2)&3)*6 + (mB&3);
  f32x4 acc[2][4] = {};

  #define WLOAD(s_, buf_) do { \
    const unsigned short* gs = wbf + (size_t)(s_)*8192 + (size_t)(wid*4*64 + lane)*8; \
    _Pragma("unroll") \
    for (int it = 0; it < 4; ++it){ \
      __builtin_amdgcn_global_load_lds( \
        (const __attribute__((address_space(1))) unsigned int*)(gs + it*512), \
        (__attribute__((address_space(3))) unsigned int*)(&wt[buf_][(wid*4+it)*512]), \
        16, 0, 0); \
    } \
  } while(0)

  int s = 0;
  WLOAD(0, 0);
  for (int h = 0; h < 2; ++h){
    for (int cidx = t; cidx < 1728; cidx += 256){
      int kgr = cidx / 216, pos = cidx % 216;
      int uz = pos / 36, r36 = pos % 36, uy = r36 / 6, ux = r36 % 6;
      int zz = z0 - 1 + uz, yy = y0 - 1 + uy, xx = x0 - 1 + ux;
      uint4 v = make_uint4(0u,0u,0u,0u);
      if (zz >= 0 && zz < 28 && yy >= 0 && yy < 28 && xx >= 0 && xx < 28)
        v = *reinterpret_cast<const uint4*>(
              &xag[(((size_t)b*SP) + zz*784 + yy*28 + xx)*128 + h*64 + kgr*8]);
      *reinterpret_cast<uint4*>(&halo[(size_t)cidx*8]) = v;
    }
    __syncthreads();
    for (int tap = 0; tap < 27; ++tap){
      if (s + 1 < 54) WLOAD(s + 1, (s + 1) & 1);
      const unsigned short* wc = wt[s & 1];
      int dz = tap / 9, r9 = tap % 9, dy = r9 / 3, dx = r9 % 3;
      int off = dz*36 + dy*6 + dx;
      #pragma unroll
      for (int ks = 0; ks < 2; ++ks){
        int ksel = ks*4 + quad;
        bf16x8 a0 = *reinterpret_cast<const bf16x8*>(&halo[(ksel*216 + hp0 + off)*8]);
        bf16x8 a1 = *reinterpret_cast<const bf16x8*>(&halo[(ksel*216 + hp1 + off)*8]);
        #pragma unroll
        for (int nt = 0; nt < 4; ++nt){
          bf16x8 bb = *reinterpret_cast<const bf16x8*>(&wc[(ksel*128 + ohalf*64 + nt*16 + nn)*8]);
          acc[0][nt] = __builtin_amdgcn_mfma_f32_16x16x32_bf16(a0, bb, acc[0][nt], 0, 0, 0);
          acc[1][nt] = __builtin_amdgcn_mfma_f32_16x16x32_bf16(a1, bb, acc[1][nt], 0, 0, 0);
        }
      }
      ++s;
      __syncthreads();
    }
  }
  #pragma unroll
  for (int mt = 0; mt < 2; ++mt){
    #pragma unroll
    for (int nt = 0; nt < 4; ++nt){
      #pragma unroll
      for (int r = 0; r < 4; ++r){
        int m = mhalf*32 + mt*16 + quad*4 + r;
        int oc = ohalf*64 + nt*16 + nn;
        int pos = (z0 + (m>>4))*784 + (y0 + ((m>>2)&3))*28 + (x0 + (m&3));
        yg[((size_t)b*SP + pos)*128 + oc] = f2b(acc[mt][nt][r]);
      }
    }
  }
  #undef WLOAD
}

// K5: per-channel sum/sumsq of y via lane-private channel partials + atomics
__global__ void k5_ystats(const unsigned short* __restrict__ yg, float* __restrict__ misc){
  int t = threadIdx.x;
  float s = 0.f, ss = 0.f;
  size_t base = (size_t)blockIdx.x * 32768 + t;
  for (int k = 0; k < 128; ++k){
    float v = b2f(yg[base + (size_t)k*256]);
    s += v; ss += v*v;
  }
  __shared__ float rs[256], rq[256];
  rs[t] = s; rq[t] = ss;
  __syncthreads();
  if (t < 128){
    atomicAdd(&misc[MISC_SUM + t], rs[t] + rs[t+128]);
    atomicAdd(&misc[MISC_SQ  + t], rq[t] + rq[t+128]);
  }
}

__global__ void k5b_finstats(const float* __restrict__ gcl, const float* __restrict__ bcl,
                             float* __restrict__ misc){
  int c = threadIdx.x;
  float mean = misc[MISC_SUM+c] / (float)PT;
  float var  = misc[MISC_SQ +c] / (float)PT - mean*mean;
  float a = gcl[c] * rsqrtf(var + EPS_);
  misc[MISC_A2+c] = a;
  misc[MISC_B2+c] = bcl[c] - mean*a;
}

// K6: out = shortcut + Wproj @ (x_att + silu(bn(y)))
__global__ __launch_bounds__(256) void k6_final(const unsigned short* __restrict__ xag,
        const unsigned short* __restrict__ yg, const float* __restrict__ wproj,
        const float* __restrict__ xin, const float* __restrict__ misc,
        float* __restrict__ out){
  __shared__ __align__(16) float tls[128*65];   // [c][p] pad 65
  __shared__ __align__(16) float wls[32*128];
  int t = threadIdx.x;
  int P0 = blockIdx.x * 64;
  int b = P0 / SP, sp0 = P0 % SP;
  for (int idx = t; idx < 8192; idx += 256){
    int c = idx & 127, p = idx >> 7;
    size_t g = (size_t)(P0 + p)*128 + c;
    float yv = b2f(yg[g]) * misc[MISC_A2+c] + misc[MISC_B2+c];
    float sil = yv / (1.f + __expf(-yv));
    tls[c*65 + p] = b2f(xag[g]) + sil;
  }
  int p = t & 63, og = t >> 6;
  for (int qtr = 0; qtr < 4; ++qtr){
    __syncthreads();
    for (int idx = t; idx < 4096; idx += 256)
      wls[idx] = wproj[qtr*4096 + idx];
    __syncthreads();
    float acc[8];
    #pragma unroll
    for (int j = 0; j < 8; ++j) acc[j] = 0.f;
    const float4* w4p = reinterpret_cast<const float4*>(wls);
    for (int cq = 0; cq < 32; ++cq){
      float x0 = tls[(cq*4+0)*65 + p];
      float x1 = tls[(cq*4+1)*65 + p];
      float x2 = tls[(cq*4+2)*65 + p];
      float x3 = tls[(cq*4+3)*65 + p];
      #pragma unroll
      for (int j = 0; j < 8; ++j){
        float4 wf = w4p[(og*8+j)*32 + cq];
        acc[j] += wf.x*x0 + wf.y*x1 + wf.z*x2 + wf.w*x3;
      }
    }
    #pragma unroll
    for (int j = 0; j < 8; ++j){
      int o = qtr*32 + og*8 + j;
      size_t gaddr = ((size_t)b*128 + o)*SP + sp0 + p;
      out[gaddr] = xin[gaddr] + acc[j];
    }
  }
}

extern "C" void kernel_launch(void* const* d_in, const int* in_sizes, int n_in,
                              void* d_out, int out_size, void* d_ws, size_t ws_size,
                              hipStream_t stream){
  const float* x      = (const float*)d_in[0];
  const float* g_in   = (const float*)d_in[1];
  const float* b_in   = (const float*)d_in[2];
  const float* w_qk   = (const float*)d_in[3];
  const float* w_v    = (const float*)d_in[4];
  const float* w_cl   = (const float*)d_in[5];
  const float* g_cl   = (const float*)d_in[6];
  const float* b_cl   = (const float*)d_in[7];
  const float* w_proj = (const float*)d_in[8];
  float* out = (float*)d_out;

  char* ws = (char*)d_ws;
  unsigned short* qg  = (unsigned short*)ws;
  unsigned short* kgp = qg  + 11239424;
  unsigned short* vg  = kgp + 11239424;
  unsigned short* xag = vg  + 11239424;
  unsigned short* yg  = xag + 11239424;
  float* misc = (float*)(ws + (size_t)5*22478848);   // 112,394,240 B offset
  unsigned short* wbf = qg;   // reuses qg region AFTER k3 consumed q
  unsigned short* w2  = yg;   // qkv hi/lo weights; yg is free until k4 writes it

  hipMemsetAsync(misc + MISC_SUM, 0, 256*sizeof(float), stream);
  k0_stats    <<<128, 256, 0, stream>>>(x, g_in, b_in, misc);
  k1_bias     <<<3, 128, 0, stream>>>(w_qk, w_v, misc);
  k1w         <<<192, 256, 0, stream>>>(w_qk, w_v, w2);
  k2_qkv      <<<1372, 256, 0, stream>>>(x, w2, misc, qg, kgp, vg);
  k3_attn     <<<1024, 256, 0, stream>>>(qg, kgp, vg, xag);
  k_wprep     <<<1728, 256, 0, stream>>>(w_cl, wbf);
  k4_mfma     <<<1372, 256, 0, stream>>>(xag, wbf, yg);
  k5_ystats   <<<343, 256, 0, stream>>>(yg, misc);
  k5b_finstats<<<1, 128, 0, stream>>>(g_cl, b_cl, misc);
  k6_final    <<<1372, 256, 0, stream>>>(xag, yg, w_proj, x, misc, out);
}

// Round 3
// 422.023 us; speedup vs baseline: 3.3067x; 1.4152x over previous
//
#include <hip/hip_runtime.h>
#include <hip/hip_bf16.h>

// Problem constants
#define C      128
#define SP     21952          // 28*28*28
#define PT     87808          // 4*SP
#define LW     343            // 7^3 window length
#define EPS_   1e-6f
#define SCALE_ 0.17677669529663687f  // 32^-0.5

// misc workspace layout (floats)
#define MISC_A   0
#define MISC_B   128
#define MISC_BQK 256
#define MISC_BV  512
#define MISC_SUM 640
#define MISC_SQ  768
#define MISC_A2  896
#define MISC_B2  1024
#define MISC_XS  1152
#define MISC_XQ  1280

typedef __attribute__((ext_vector_type(8))) short bf16x8;
typedef __attribute__((ext_vector_type(4))) float f32x4;

__device__ __forceinline__ float b2f(unsigned short u){
  return __uint_as_float(((unsigned int)u) << 16);
}
__device__ __forceinline__ unsigned short f2b(float f){
  unsigned int u = __float_as_uint(f);
  u += 0x7fffu + ((u >> 16) & 1u);     // round-to-nearest-even
  return (unsigned short)(u >> 16);
}

// K0 (rewritten): per-channel partial sum/sumsq of x, 1024 blocks, float4 loads.
// Old version was 128 blocks of scalar loads: 2 waves/CU, latency-bound, 143us
// at 2% of HBM peak. This: 8 chunks x 128 channels, 16B/lane, atomics finalize.
__global__ __launch_bounds__(256) void k0_partial(const float* __restrict__ x,
                                                  float* __restrict__ misc){
  int c = blockIdx.x & 127, chunk = blockIdx.x >> 7;   // 8 chunks = 4 batch x 2 halves
  int bb = chunk >> 1, half = chunk & 1;
  const float4* p = reinterpret_cast<const float4*>(
      x + (size_t)(bb*C + c)*SP + half*10976);
  int t = threadIdx.x;
  float s = 0.f, ss = 0.f;
  for (int i = t; i < 2744; i += 256){
    float4 v = p[i];
    s  += v.x + v.y + v.z + v.w;
    ss += v.x*v.x + v.y*v.y + v.z*v.z + v.w*v.w;
  }
  #pragma unroll
  for (int off = 32; off > 0; off >>= 1){
    s  += __shfl_xor(s,  off);
    ss += __shfl_xor(ss, off);
  }
  __shared__ float red[8];
  int wid = t >> 6, lane = t & 63;
  if (lane == 0){ red[wid] = s; red[4+wid] = ss; }
  __syncthreads();
  if (t == 0){
    atomicAdd(&misc[MISC_XS + c], red[0]+red[1]+red[2]+red[3]);
    atomicAdd(&misc[MISC_XQ + c], red[4]+red[5]+red[6]+red[7]);
  }
}

// K1: finalize BN stats (from k0 partials) + fold shift through 1x1 weights.
__global__ void k1_bias(const float* __restrict__ wqk, const float* __restrict__ wvv,
                        const float* __restrict__ gin, const float* __restrict__ bin,
                        float* __restrict__ misc){
  __shared__ float bv[128];
  int t = threadIdx.x;          // 128 threads, grid 3
  {
    float mean = misc[MISC_XS + t] / (float)PT;
    float var  = misc[MISC_XQ + t] / (float)PT - mean*mean;
    float a = rsqrtf(var + EPS_) * gin[t];
    float bb = bin[t] - mean * a;
    bv[t] = bb;
    if (blockIdx.x == 0){ misc[MISC_A + t] = a; misc[MISC_B + t] = bb; }
  }
  __syncthreads();
  int o = blockIdx.x*128 + t;
  float acc = 0.f;
  if (o < 256){
    const float* wr = wqk + (size_t)o*128;
    for (int c = 0; c < 128; ++c) acc += wr[c]*bv[c];
    misc[MISC_BQK + o] = acc;
  } else {
    const float* wr = wvv + (size_t)(o-256)*128;
    for (int c = 0; c < 128; ++c) acc += wr[c]*bv[c];
    misc[MISC_BV + (o-256)] = acc;
  }
}

// K1w: split qkv weights into bf16 hi/lo pairs: w2[0..49152) = hi, [49152..) = lo
__global__ void k1w(const float* __restrict__ wqk, const float* __restrict__ wvv,
                    unsigned short* __restrict__ w2){
  int idx = blockIdx.x*256 + threadIdx.x;   // 49152 total
  int o = idx >> 7;
  float w = (o < 256) ? wqk[idx] : wvv[idx - 32768];
  unsigned short h = f2b(w);
  w2[idx] = h;
  w2[49152 + idx] = f2b(w - b2f(h));
}

// K2 (MFMA): qkv projection on mfma_f32_16x16x32_bf16 with split-bf16
// fp32 emulation: out = xh*wh + xl*wh + xh*wl (missing xl*wl ~ 2^-18 relative).
__global__ __launch_bounds__(256) void k2_qkv(const float* __restrict__ x,
        const unsigned short* __restrict__ w2, const float* __restrict__ misc,
        unsigned short* __restrict__ qg, unsigned short* __restrict__ kg,
        unsigned short* __restrict__ vg){
  __shared__ __align__(16) unsigned short xh[8192];   // 16KB
  __shared__ __align__(16) unsigned short xl[8192];   // 16KB
  __shared__ float ascale[128];
  __shared__ unsigned int posTab[64];
  int t = threadIdx.x;
  int P0 = blockIdx.x * 64;
  int b = P0 / SP, sp0 = P0 % SP;
  if (t < 128) ascale[t] = misc[MISC_A + t];
  if (t < 64){
    int sp = sp0 + t;
    int h_ = sp / 784, rem = sp % 784;
    int w_ = rem / 28, d_ = rem % 28;
    int w1 = h_ & 3, s1 = h_ >> 2;
    int w2i = w_ & 3, s2 = w_ >> 2;
    int w3 = d_ & 3, s3 = d_ >> 2;
    int bw = ((b*4 + w1)*4 + w2i)*4 + w3;
    int l  = (s1*7 + s2)*7 + s3;
    posTab[t] = (unsigned int)(bw*43904 + l*32);   // ushort offset, +h*10976+d at store
  }
  __syncthreads();
  // stage x -> bf16 hi/lo (BN scale folded), swizzled
  {
    int p = t & 63;
    int ob = t >> 6;
    const float* xb = x + (size_t)b*C*SP + sp0 + p;
    for (int it = 0; it < 4; ++it){
      int c0 = (ob + it*4) * 8;
      unsigned int ph[4], pl[4];
      #pragma unroll
      for (int j = 0; j < 4; ++j){
        float f0 = xb[(size_t)(c0 + 2*j)*SP]     * ascale[c0 + 2*j];
        float f1 = xb[(size_t)(c0 + 2*j + 1)*SP] * ascale[c0 + 2*j + 1];
        unsigned short h0 = f2b(f0), h1 = f2b(f1);
        unsigned short l0 = f2b(f0 - b2f(h0)), l1 = f2b(f1 - b2f(h1));
        ph[j] = (unsigned int)h0 | ((unsigned int)h1 << 16);
        pl[j] = (unsigned int)l0 | ((unsigned int)l1 << 16);
      }
      int byte = (p*256 + c0*2) ^ ((p & 7) << 4);
      *reinterpret_cast<uint4*>((char*)xh + byte) = make_uint4(ph[0],ph[1],ph[2],ph[3]);
      *reinterpret_cast<uint4*>((char*)xl + byte) = make_uint4(pl[0],pl[1],pl[2],pl[3]);
    }
  }
  __syncthreads();
  int wid = t >> 6, lane = t & 63;
  int g = lane >> 4, ln = lane & 15;
  int wstart = wid * 96;
  f32x4 acc[6][4];
  #pragma unroll
  for (int nt = 0; nt < 6; ++nt){
    float bv = misc[256 + wstart + nt*16 + ln];
    #pragma unroll
    for (int mt = 0; mt < 4; ++mt) acc[nt][mt] = (f32x4){bv,bv,bv,bv};
  }
  #pragma unroll 1
  for (int kk = 0; kk < 4; ++kk){
    bf16x8 ah[4], al[4];
    #pragma unroll
    for (int mt = 0; mt < 4; ++mt){
      int row = mt*16 + ln;
      int byte = (row*256 + kk*64 + g*16) ^ ((ln & 7) << 4);
      ah[mt] = *reinterpret_cast<const bf16x8*>((const char*)xh + byte);
      al[mt] = *reinterpret_cast<const bf16x8*>((const char*)xl + byte);
    }
    #pragma unroll
    for (int nt = 0; nt < 6; ++nt){
      int o = wstart + nt*16 + ln;
      const unsigned short* wp = w2 + (size_t)o*128 + kk*32 + g*8;
      bf16x8 whf = *reinterpret_cast<const bf16x8*>(wp);
      bf16x8 wlf = *reinterpret_cast<const bf16x8*>(wp + 49152);
      #pragma unroll
      for (int mt = 0; mt < 4; ++mt){
        acc[nt][mt] = __builtin_amdgcn_mfma_f32_16x16x32_bf16(ah[mt], whf, acc[nt][mt], 0, 0, 0);
        acc[nt][mt] = __builtin_amdgcn_mfma_f32_16x16x32_bf16(al[mt], whf, acc[nt][mt], 0, 0, 0);
        acc[nt][mt] = __builtin_amdgcn_mfma_f32_16x16x32_bf16(ah[mt], wlf, acc[nt][mt], 0, 0, 0);
      }
    }
  }
  // epilogue: relu on v, bf16, scatter (16 consecutive lanes = 32B contiguous)
  unsigned int ptab[16];
  #pragma unroll
  for (int mt = 0; mt < 4; ++mt)
    #pragma unroll
    for (int r = 0; r < 4; ++r)
      ptab[mt*4+r] = posTab[mt*16 + g*4 + r];
  #pragma unroll
  for (int nt = 0; nt < 6; ++nt){
    int o = wstart + nt*16 + ln;
    bool isv = (o >= 256);
    int oo = o & 127;
    unsigned short* dst = ((o < 128) ? qg : (o < 256 ? kg : vg)) + (oo >> 5)*10976 + (oo & 31);
    #pragma unroll
    for (int mt = 0; mt < 4; ++mt){
      #pragma unroll
      for (int r = 0; r < 4; ++r){
        float v = acc[nt][mt][r];
        if (isv) v = fmaxf(v, 0.f);
        dst[ptab[mt*4+r]] = f2b(v);
      }
    }
  }
}

// K3 (MFMA): attention per (window, head) on mfma_f32_16x16x32_bf16.
__global__ __launch_bounds__(256) void k3_attn(const unsigned short* __restrict__ qg,
        const unsigned short* __restrict__ kg, const unsigned short* __restrict__ vg,
        unsigned short* __restrict__ xatt){
  __shared__ __align__(16) unsigned short klds[352*32];    // [m][d]     22528 B
  __shared__ __align__(16) unsigned short vper[32*360];    // [d][m']    23040 B
  __shared__ __align__(16) unsigned short pbuf[4][640];    // per-wave [16][40]
  int bh = blockIdx.x;
  int bw = bh >> 2, h = bh & 3;
  int t = threadIdx.x;
  int wid = t >> 6, lane = t & 63;
  int g = lane >> 4, ln = lane & 15;
  const unsigned short* kbase = kg + (size_t)bh*LW*32;
  const unsigned short* vbase = vg + (size_t)bh*LW*32;
  const unsigned short* qbase = qg + (size_t)bh*LW*32;
  // stage K: straight uint4 copy, zero pad rows 343..351
  {
    const uint4* src = reinterpret_cast<const uint4*>(kbase);
    uint4* dst = reinterpret_cast<uint4*>(klds);
    for (int i = t; i < 1372; i += 256) dst[i] = src[i];
    for (int i = t; i < 288; i += 256) klds[10976 + i] = 0;
  }
  // stage V transposed + 32-key interleave: m -> (c = m>>5, pk = 2*(m&15) | ((m>>4)&1))
  for (int idx = t; idx < 10976; idx += 256){
    int m = idx >> 5, d = idx & 31;
    int km = m & 31;
    int pk = ((km & 15) << 1) | (km >> 4);
    vper[d*360 + ((m >> 5) << 5) + pk] = vbase[idx];
  }
  for (int i = t; i < 288; i += 256){       // zero V pad rows 343..351
    int m = 343 + (i >> 5), d = i & 31;
    int km = m & 31;
    int pk = ((km & 15) << 1) | (km >> 4);
    vper[d*360 + 320 + pk] = 0;
  }
  __syncthreads();
  int w1 = (bw>>4)&3, w2 = (bw>>2)&3, w3 = bw&3, b = bw>>6;
  unsigned short* pb = pbuf[wid];
  const f32x4 zero4 = {0.f, 0.f, 0.f, 0.f};
  for (int rt = wid; rt < 22; rt += 4){
    int row0 = rt << 4;
    bf16x8 qf = *reinterpret_cast<const bf16x8*>(qbase + (size_t)(row0 + ln)*32 + g*8);
    // QK^T: 22 n-tiles, single k-step (K=32=DH)
    f32x4 s[22];
    #pragma unroll
    for (int nt = 0; nt < 22; ++nt){
      bf16x8 kf = *reinterpret_cast<const bf16x8*>(&klds[(nt*16 + ln)*32 + g*8]);
      s[nt] = __builtin_amdgcn_mfma_f32_16x16x32_bf16(qf, kf, zero4, 0, 0, 0);
    }
    float mxs[4];
    #pragma unroll
    for (int q = 0; q < 4; ++q){
      float m0 = -1e30f;
      #pragma unroll
      for (int nt = 0; nt < 21; ++nt) m0 = fmaxf(m0, s[nt][q]);
      if (ln < 7) m0 = fmaxf(m0, s[21][q]);
      #pragma unroll
      for (int off = 8; off > 0; off >>= 1) m0 = fmaxf(m0, __shfl_xor(m0, off));
      mxs[q] = m0 * SCALE_;
    }
    f32x4 o0 = zero4, o1 = zero4;
    float sums[4] = {0.f, 0.f, 0.f, 0.f};
    #pragma unroll
    for (int c = 0; c < 11; ++c){
      #pragma unroll
      for (int q = 0; q < 4; ++q){
        float e0 = __expf(fmaf(s[2*c][q],   SCALE_, -mxs[q]));
        float e1 = (c*32 + 16 + ln < 343)
                 ? __expf(fmaf(s[2*c+1][q], SCALE_, -mxs[q])) : 0.f;
        sums[q] += e0 + e1;
        unsigned int pkd;
        asm volatile("v_cvt_pk_bf16_f32 %0, %1, %2" : "=v"(pkd) : "v"(e0), "v"(e1));
        *reinterpret_cast<unsigned int*>(&pb[(g*4+q)*40 + (ln<<1)]) = pkd;
      }
      asm volatile("s_waitcnt lgkmcnt(0)" ::: "memory");
      __builtin_amdgcn_sched_barrier(0);
      bf16x8 pa  = *reinterpret_cast<const bf16x8*>(&pb[ln*40 + g*8]);
      bf16x8 vb0 = *reinterpret_cast<const bf16x8*>(&vper[ln*360       + (c<<5) + g*8]);
      bf16x8 vb1 = *reinterpret_cast<const bf16x8*>(&vper[(16+ln)*360  + (c<<5) + g*8]);
      o0 = __builtin_amdgcn_mfma_f32_16x16x32_bf16(pa, vb0, o0, 0, 0, 0);
      o1 = __builtin_amdgcn_mfma_f32_16x16x32_bf16(pa, vb1, o1, 0, 0, 0);
    }
    float iss[4];
    #pragma unroll
    for (int q = 0; q < 4; ++q){
      float sq = sums[q];
      #pragma unroll
      for (int off = 8; off > 0; off >>= 1) sq += __shfl_xor(sq, off);
      iss[q] = 1.f / sq;
    }
    #pragma unroll
    for (int q = 0; q < 4; ++q){
      int l = row0 + g*4 + q;
      if (l < 343){
        int ss1 = l/49, ss2 = (l/7)%7, ss3 = l%7;
        int sp = (ss1*4+w1)*784 + (ss2*4+w2)*28 + (ss3*4+w3);
        size_t gaddr = ((size_t)b*SP + sp)*128 + h*32;
        xatt[gaddr + ln]      = f2b(o0[q]*iss[q]);
        xatt[gaddr + 16 + ln] = f2b(o1[q]*iss[q]);
      }
    }
  }
}

// K_wprep: w_cl [oc][ic][27] fp32 -> wbf bf16 slices [h][tap][kg][oc][8]
__global__ void k_wprep(const float* __restrict__ wcl, unsigned short* __restrict__ wbf){
  int f = blockIdx.x*256 + threadIdx.x;      // 442368 total
  int j  = f & 7;
  int oc = (f >> 3) & 127;
  int kgr= (f >> 10) & 7;
  int sl = f >> 13;                          // 0..53
  int h  = sl / 27, tap = sl % 27;
  int ic = h*64 + kgr*8 + j;
  wbf[f] = f2b(wcl[((size_t)oc*128 + ic)*27 + tap]);
}

// K6w: split proj weights into bf16 hi/lo pairs: w6[0..16384) hi, [16384..) lo
__global__ void k6w(const float* __restrict__ wproj, unsigned short* __restrict__ w6){
  int idx = blockIdx.x*256 + threadIdx.x;   // 16384 total
  float w = wproj[idx];
  unsigned short h = f2b(w);
  w6[idx] = h;
  w6[16384 + idx] = f2b(w - b2f(h));
}

// K4: 3x3x3 conv as implicit GEMM on mfma_f32_16x16x32_bf16.
__global__ __launch_bounds__(256) void k4_mfma(const unsigned short* __restrict__ xag,
        const unsigned short* __restrict__ wbf, unsigned short* __restrict__ yg){
  __shared__ __align__(16) unsigned short halo[8*216*8];   // 27648 B
  __shared__ __align__(16) unsigned short wt[2][8192];     // 2 x 16384 B
  int t = threadIdx.x, wid = t >> 6, lane = t & 63;
  int stile = blockIdx.x;
  int b = stile / 343, srem = stile % 343;
  int z0 = (srem/49)*4, y0 = ((srem/7)%7)*4, x0 = (srem%7)*4;
  int mhalf = wid & 1, ohalf = wid >> 1;
  int nn = lane & 15, quad = lane >> 4;
  int mA = mhalf*32 + nn;          // m-tile 0 row of this lane
  int mB = mA + 16;                // m-tile 1 row
  int hp0 = (mA>>4)*36 + ((mA>>2)&3)*6 + (mA&3);
  int hp1 = (mB>>4)*36 + ((mB>>2)&3)*6 + (mB&3);
  f32x4 acc[2][4] = {};

  #define WLOAD(s_, buf_) do { \
    const unsigned short* gs = wbf + (size_t)(s_)*8192 + (size_t)(wid*4*64 + lane)*8; \
    _Pragma("unroll") \
    for (int it = 0; it < 4; ++it){ \
      __builtin_amdgcn_global_load_lds( \
        (const __attribute__((address_space(1))) unsigned int*)(gs + it*512), \
        (__attribute__((address_space(3))) unsigned int*)(&wt[buf_][(wid*4+it)*512]), \
        16, 0, 0); \
    } \
  } while(0)

  int s = 0;
  WLOAD(0, 0);
  for (int h = 0; h < 2; ++h){
    for (int cidx = t; cidx < 1728; cidx += 256){
      int kgr = cidx / 216, pos = cidx % 216;
      int uz = pos / 36, r36 = pos % 36, uy = r36 / 6, ux = r36 % 6;
      int zz = z0 - 1 + uz, yy = y0 - 1 + uy, xx = x0 - 1 + ux;
      uint4 v = make_uint4(0u,0u,0u,0u);
      if (zz >= 0 && zz < 28 && yy >= 0 && yy < 28 && xx >= 0 && xx < 28)
        v = *reinterpret_cast<const uint4*>(
              &xag[(((size_t)b*SP) + zz*784 + yy*28 + xx)*128 + h*64 + kgr*8]);
      *reinterpret_cast<uint4*>(&halo[(size_t)cidx*8]) = v;
    }
    __syncthreads();
    for (int tap = 0; tap < 27; ++tap){
      if (s + 1 < 54) WLOAD(s + 1, (s + 1) & 1);
      const unsigned short* wc = wt[s & 1];
      int dz = tap / 9, r9 = tap % 9, dy = r9 / 3, dx = r9 % 3;
      int off = dz*36 + dy*6 + dx;
      #pragma unroll
      for (int ks = 0; ks < 2; ++ks){
        int ksel = ks*4 + quad;
        bf16x8 a0 = *reinterpret_cast<const bf16x8*>(&halo[(ksel*216 + hp0 + off)*8]);
        bf16x8 a1 = *reinterpret_cast<const bf16x8*>(&halo[(ksel*216 + hp1 + off)*8]);
        #pragma unroll
        for (int nt = 0; nt < 4; ++nt){
          bf16x8 bb = *reinterpret_cast<const bf16x8*>(&wc[(ksel*128 + ohalf*64 + nt*16 + nn)*8]);
          acc[0][nt] = __builtin_amdgcn_mfma_f32_16x16x32_bf16(a0, bb, acc[0][nt], 0, 0, 0);
          acc[1][nt] = __builtin_amdgcn_mfma_f32_16x16x32_bf16(a1, bb, acc[1][nt], 0, 0, 0);
        }
      }
      ++s;
      __syncthreads();
    }
  }
  #pragma unroll
  for (int mt = 0; mt < 2; ++mt){
    #pragma unroll
    for (int nt = 0; nt < 4; ++nt){
      #pragma unroll
      for (int r = 0; r < 4; ++r){
        int m = mhalf*32 + mt*16 + quad*4 + r;
        int oc = ohalf*64 + nt*16 + nn;
        int pos = (z0 + (m>>4))*784 + (y0 + ((m>>2)&3))*28 + (x0 + (m&3));
        yg[((size_t)b*SP + pos)*128 + oc] = f2b(acc[mt][nt][r]);
      }
    }
  }
  #undef WLOAD
}

// K5: per-channel sum/sumsq of y via lane-private channel partials + atomics
__global__ void k5_ystats(const unsigned short* __restrict__ yg, float* __restrict__ misc){
  int t = threadIdx.x;
  float s = 0.f, ss = 0.f;
  size_t base = (size_t)blockIdx.x * 32768 + t;
  for (int k = 0; k < 128; ++k){
    float v = b2f(yg[base + (size_t)k*256]);
    s += v; ss += v*v;
  }
  __shared__ float rs[256], rq[256];
  rs[t] = s; rq[t] = ss;
  __syncthreads();
  if (t < 128){
    atomicAdd(&misc[MISC_SUM + t], rs[t] + rs[t+128]);
    atomicAdd(&misc[MISC_SQ  + t], rq[t] + rq[t+128]);
  }
}

__global__ void k5b_finstats(const float* __restrict__ gcl, const float* __restrict__ bcl,
                             float* __restrict__ misc){
  int c = threadIdx.x;
  float mean = misc[MISC_SUM+c] / (float)PT;
  float var  = misc[MISC_SQ +c] / (float)PT - mean*mean;
  float a = gcl[c] * rsqrtf(var + EPS_);
  misc[MISC_A2+c] = a;
  misc[MISC_B2+c] = bcl[c] - mean*a;
}

// K6 (MFMA rewrite): out = shortcut + Wproj @ (x_att + silu(bn(y))) with
// split-bf16 fp32 emulation (same scheme as k2: wh*bh + wl*bh + wh*bl).
//   A-frag (Wproj): row = o (lane&15), k = (lane>>4)*8+i, straight from global
//     (32KB hi+lo, L2-hot across all 1372 blocks).
//   B-frag (X): col = position (lane&15), same k, from LDS [64][128] bf16
//     XOR-swizzled byte^=((pos&7)<<4).
//   D: row = o ((lane>>4)*4+reg), col = position (lane&15) -> stores along sp,
//     16 consecutive lanes = 64B contiguous fp32 runs (coalesced, same as xin).
__global__ __launch_bounds__(256) void k6_final(const unsigned short* __restrict__ xag,
        const unsigned short* __restrict__ yg, const unsigned short* __restrict__ w6,
        const float* __restrict__ xin, const float* __restrict__ misc,
        float* __restrict__ out){
  __shared__ __align__(16) unsigned short xh[8192];   // 16KB
  __shared__ __align__(16) unsigned short xl[8192];   // 16KB
  __shared__ float a2s[128], b2s[128];
  int t = threadIdx.x;
  int P0 = blockIdx.x * 64;
  int b = P0 / SP, sp0 = P0 % SP;
  if (t < 128){ a2s[t] = misc[MISC_A2+t]; b2s[t] = misc[MISC_B2+t]; }
  __syncthreads();
  // stage: v = xatt + silu(bn(y)) -> bf16 hi/lo, swizzled [pos][c]
  for (int idx = t; idx < 1024; idx += 256){
    int p = idx >> 4, c0 = (idx & 15) * 8;
    size_t gb = (size_t)(P0 + p)*128 + c0;
    uint4 yv4 = *reinterpret_cast<const uint4*>(yg + gb);
    uint4 xa4 = *reinterpret_cast<const uint4*>(xag + gb);
    unsigned int ph[4], pl[4];
    #pragma unroll
    for (int j = 0; j < 4; ++j){
      unsigned int uy = (&yv4.x)[j], ux = (&xa4.x)[j];
      int c = c0 + 2*j;
      float y0 = __uint_as_float(uy << 16)          * a2s[c]   + b2s[c];
      float y1 = __uint_as_float(uy & 0xffff0000u)  * a2s[c+1] + b2s[c+1];
      float v0 = __uint_as_float(ux << 16)         + y0 / (1.f + __expf(-y0));
      float v1 = __uint_as_float(ux & 0xffff0000u) + y1 / (1.f + __expf(-y1));
      unsigned short h0 = f2b(v0), h1 = f2b(v1);
      unsigned short l0 = f2b(v0 - b2f(h0)), l1 = f2b(v1 - b2f(h1));
      ph[j] = (unsigned int)h0 | ((unsigned int)h1 << 16);
      pl[j] = (unsigned int)l0 | ((unsigned int)l1 << 16);
    }
    int byte = (p*256 + c0*2) ^ ((p & 7) << 4);
    *reinterpret_cast<uint4*>((char*)xh + byte) = make_uint4(ph[0],ph[1],ph[2],ph[3]);
    *reinterpret_cast<uint4*>((char*)xl + byte) = make_uint4(pl[0],pl[1],pl[2],pl[3]);
  }
  __syncthreads();
  int wid = t >> 6, lane = t & 63;
  int g = lane >> 4, ln = lane & 15;
  f32x4 acc[2][4] = {};    // [o-tile][pos-tile]
  #pragma unroll 1
  for (int kk = 0; kk < 4; ++kk){
    bf16x8 bh[4], bl[4];
    #pragma unroll
    for (int pt = 0; pt < 4; ++pt){
      int row = pt*16 + ln;
      int byte = (row*256 + kk*64 + g*16) ^ ((ln & 7) << 4);
      bh[pt] = *reinterpret_cast<const bf16x8*>((const char*)xh + byte);
      bl[pt] = *reinterpret_cast<const bf16x8*>((const char*)xl + byte);
    }
    #pragma unroll
    for (int ot = 0; ot < 2; ++ot){
      int o = wid*32 + ot*16 + ln;
      const unsigned short* wp = w6 + (size_t)o*128 + kk*32 + g*8;
      bf16x8 wh = *reinterpret_cast<const bf16x8*>(wp);
      bf16x8 wl = *reinterpret_cast<const bf16x8*>(wp + 16384);
      #pragma unroll
      for (int pt = 0; pt < 4; ++pt){
        acc[ot][pt] = __builtin_amdgcn_mfma_f32_16x16x32_bf16(wh, bh[pt], acc[ot][pt], 0, 0, 0);
        acc[ot][pt] = __builtin_amdgcn_mfma_f32_16x16x32_bf16(wl, bh[pt], acc[ot][pt], 0, 0, 0);
        acc[ot][pt] = __builtin_amdgcn_mfma_f32_16x16x32_bf16(wh, bl[pt], acc[ot][pt], 0, 0, 0);
      }
    }
  }
  #pragma unroll
  for (int ot = 0; ot < 2; ++ot){
    #pragma unroll
    for (int r = 0; r < 4; ++r){
      int o = wid*32 + ot*16 + g*4 + r;
      size_t gbase = ((size_t)b*128 + o)*SP + sp0;
      #pragma unroll
      for (int pt = 0; pt < 4; ++pt){
        size_t gaddr = gbase + pt*16 + ln;
        out[gaddr] = xin[gaddr] + acc[ot][pt][r];
      }
    }
  }
}

extern "C" void kernel_launch(void* const* d_in, const int* in_sizes, int n_in,
                              void* d_out, int out_size, void* d_ws, size_t ws_size,
                              hipStream_t stream){
  const float* x      = (const float*)d_in[0];
  const float* g_in   = (const float*)d_in[1];
  const float* b_in   = (const float*)d_in[2];
  const float* w_qk   = (const float*)d_in[3];
  const float* w_v    = (const float*)d_in[4];
  const float* w_cl   = (const float*)d_in[5];
  const float* g_cl   = (const float*)d_in[6];
  const float* b_cl   = (const float*)d_in[7];
  const float* w_proj = (const float*)d_in[8];
  float* out = (float*)d_out;

  char* ws = (char*)d_ws;
  unsigned short* qg  = (unsigned short*)ws;
  unsigned short* kgp = qg  + 11239424;
  unsigned short* vg  = kgp + 11239424;
  unsigned short* xag = vg  + 11239424;
  unsigned short* yg  = xag + 11239424;
  float* misc = (float*)(ws + (size_t)5*22478848);   // 112,394,240 B offset
  unsigned short* wbf = qg;            // reuses qg region AFTER k3 consumed q
  unsigned short* w6  = qg + 524288;   // proj hi/lo weights, past wbf's 442368
  unsigned short* w2  = yg;            // qkv hi/lo weights; yg free until k4

  hipMemsetAsync(misc + MISC_SUM, 0, 768*sizeof(float), stream);
  k0_partial  <<<1024, 256, 0, stream>>>(x, misc);
  k1_bias     <<<3, 128, 0, stream>>>(w_qk, w_v, g_in, b_in, misc);
  k1w         <<<192, 256, 0, stream>>>(w_qk, w_v, w2);
  k2_qkv      <<<1372, 256, 0, stream>>>(x, w2, misc, qg, kgp, vg);
  k3_attn     <<<1024, 256, 0, stream>>>(qg, kgp, vg, xag);
  k_wprep     <<<1728, 256, 0, stream>>>(w_cl, wbf);
  k6w         <<<64, 256, 0, stream>>>(w_proj, w6);
  k4_mfma     <<<1372, 256, 0, stream>>>(xag, wbf, yg);
  k5_ystats   <<<343, 256, 0, stream>>>(yg, misc);
  k5b_finstats<<<1, 128, 0, stream>>>(g_cl, b_cl, misc);
  k6_final    <<<1372, 256, 0, stream>>>(xag, yg, w6, x, misc, out);
}

// Round 4
// 391.674 us; speedup vs baseline: 3.5630x; 1.0775x over previous
//
#include <hip/hip_runtime.h>
#include <hip/hip_bf16.h>

// Problem constants
#define C      128
#define SP     21952          // 28*28*28
#define PT     87808          // 4*SP
#define LW     343            // 7^3 window length
#define EPS_   1e-6f
#define SCALE_ 0.17677669529663687f  // 32^-0.5

// misc workspace layout (floats)
#define MISC_A   0
#define MISC_B   128
#define MISC_BQK 256
#define MISC_BV  512
#define MISC_SUM 640
#define MISC_SQ  768
#define MISC_A2  896
#define MISC_B2  1024
#define MISC_XS  1152
#define MISC_XQ  1280

typedef __attribute__((ext_vector_type(8))) short bf16x8;
typedef __attribute__((ext_vector_type(4))) float f32x4;

__device__ __forceinline__ float b2f(unsigned short u){
  return __uint_as_float(((unsigned int)u) << 16);
}
__device__ __forceinline__ unsigned short f2b(float f){
  unsigned int u = __float_as_uint(f);
  u += 0x7fffu + ((u >> 16) & 1u);     // round-to-nearest-even
  return (unsigned short)(u >> 16);
}

// K0: per-channel partial sum/sumsq of x, 1024 blocks, float4 loads.
__global__ __launch_bounds__(256) void k0_partial(const float* __restrict__ x,
                                                  float* __restrict__ misc){
  int c = blockIdx.x & 127, chunk = blockIdx.x >> 7;   // 8 chunks = 4 batch x 2 halves
  int bb = chunk >> 1, half = chunk & 1;
  const float4* p = reinterpret_cast<const float4*>(
      x + (size_t)(bb*C + c)*SP + half*10976);
  int t = threadIdx.x;
  float s = 0.f, ss = 0.f;
  for (int i = t; i < 2744; i += 256){
    float4 v = p[i];
    s  += v.x + v.y + v.z + v.w;
    ss += v.x*v.x + v.y*v.y + v.z*v.z + v.w*v.w;
  }
  #pragma unroll
  for (int off = 32; off > 0; off >>= 1){
    s  += __shfl_xor(s,  off);
    ss += __shfl_xor(ss, off);
  }
  __shared__ float red[8];
  int wid = t >> 6, lane = t & 63;
  if (lane == 0){ red[wid] = s; red[4+wid] = ss; }
  __syncthreads();
  if (t == 0){
    atomicAdd(&misc[MISC_XS + c], red[0]+red[1]+red[2]+red[3]);
    atomicAdd(&misc[MISC_XQ + c], red[4]+red[5]+red[6]+red[7]);
  }
}

// K1: finalize BN stats (from k0 partials) + fold shift through 1x1 weights.
__global__ void k1_bias(const float* __restrict__ wqk, const float* __restrict__ wvv,
                        const float* __restrict__ gin, const float* __restrict__ bin,
                        float* __restrict__ misc){
  __shared__ float bv[128];
  int t = threadIdx.x;          // 128 threads, grid 3
  {
    float mean = misc[MISC_XS + t] / (float)PT;
    float var  = misc[MISC_XQ + t] / (float)PT - mean*mean;
    float a = rsqrtf(var + EPS_) * gin[t];
    float bb = bin[t] - mean * a;
    bv[t] = bb;
    if (blockIdx.x == 0){ misc[MISC_A + t] = a; misc[MISC_B + t] = bb; }
  }
  __syncthreads();
  int o = blockIdx.x*128 + t;
  float acc = 0.f;
  if (o < 256){
    const float* wr = wqk + (size_t)o*128;
    for (int c = 0; c < 128; ++c) acc += wr[c]*bv[c];
    misc[MISC_BQK + o] = acc;
  } else {
    const float* wr = wvv + (size_t)(o-256)*128;
    for (int c = 0; c < 128; ++c) acc += wr[c]*bv[c];
    misc[MISC_BV + (o-256)] = acc;
  }
}

// K1w: split qkv weights into bf16 hi/lo pairs: w2[0..49152) = hi, [49152..) = lo
__global__ void k1w(const float* __restrict__ wqk, const float* __restrict__ wvv,
                    unsigned short* __restrict__ w2){
  int idx = blockIdx.x*256 + threadIdx.x;   // 49152 total
  int o = idx >> 7;
  float w = (o < 256) ? wqk[idx] : wvv[idx - 32768];
  unsigned short h = f2b(w);
  w2[idx] = h;
  w2[49152 + idx] = f2b(w - b2f(h));
}

// K2 (MFMA): qkv projection on mfma_f32_16x16x32_bf16 with split-bf16
// fp32 emulation: out = xh*wh + xl*wh + xh*wl (missing xl*wl ~ 2^-18 relative).
__global__ __launch_bounds__(256) void k2_qkv(const float* __restrict__ x,
        const unsigned short* __restrict__ w2, const float* __restrict__ misc,
        unsigned short* __restrict__ qg, unsigned short* __restrict__ kg,
        unsigned short* __restrict__ vg){
  __shared__ __align__(16) unsigned short xh[8192];   // 16KB
  __shared__ __align__(16) unsigned short xl[8192];   // 16KB
  __shared__ float ascale[128];
  __shared__ unsigned int posTab[64];
  int t = threadIdx.x;
  int P0 = blockIdx.x * 64;
  int b = P0 / SP, sp0 = P0 % SP;
  if (t < 128) ascale[t] = misc[MISC_A + t];
  if (t < 64){
    int sp = sp0 + t;
    int h_ = sp / 784, rem = sp % 784;
    int w_ = rem / 28, d_ = rem % 28;
    int w1 = h_ & 3, s1 = h_ >> 2;
    int w2i = w_ & 3, s2 = w_ >> 2;
    int w3 = d_ & 3, s3 = d_ >> 2;
    int bw = ((b*4 + w1)*4 + w2i)*4 + w3;
    int l  = (s1*7 + s2)*7 + s3;
    posTab[t] = (unsigned int)(bw*43904 + l*32);   // ushort offset, +h*10976+d at store
  }
  __syncthreads();
  // stage x -> bf16 hi/lo (BN scale folded), swizzled
  {
    int p = t & 63;
    int ob = t >> 6;
    const float* xb = x + (size_t)b*C*SP + sp0 + p;
    for (int it = 0; it < 4; ++it){
      int c0 = (ob + it*4) * 8;
      unsigned int ph[4], pl[4];
      #pragma unroll
      for (int j = 0; j < 4; ++j){
        float f0 = xb[(size_t)(c0 + 2*j)*SP]     * ascale[c0 + 2*j];
        float f1 = xb[(size_t)(c0 + 2*j + 1)*SP] * ascale[c0 + 2*j + 1];
        unsigned short h0 = f2b(f0), h1 = f2b(f1);
        unsigned short l0 = f2b(f0 - b2f(h0)), l1 = f2b(f1 - b2f(h1));
        ph[j] = (unsigned int)h0 | ((unsigned int)h1 << 16);
        pl[j] = (unsigned int)l0 | ((unsigned int)l1 << 16);
      }
      int byte = (p*256 + c0*2) ^ ((p & 7) << 4);
      *reinterpret_cast<uint4*>((char*)xh + byte) = make_uint4(ph[0],ph[1],ph[2],ph[3]);
      *reinterpret_cast<uint4*>((char*)xl + byte) = make_uint4(pl[0],pl[1],pl[2],pl[3]);
    }
  }
  __syncthreads();
  int wid = t >> 6, lane = t & 63;
  int g = lane >> 4, ln = lane & 15;
  int wstart = wid * 96;
  f32x4 acc[6][4];
  #pragma unroll
  for (int nt = 0; nt < 6; ++nt){
    float bv = misc[256 + wstart + nt*16 + ln];
    #pragma unroll
    for (int mt = 0; mt < 4; ++mt) acc[nt][mt] = (f32x4){bv,bv,bv,bv};
  }
  #pragma unroll 1
  for (int kk = 0; kk < 4; ++kk){
    bf16x8 ah[4], al[4];
    #pragma unroll
    for (int mt = 0; mt < 4; ++mt){
      int row = mt*16 + ln;
      int byte = (row*256 + kk*64 + g*16) ^ ((ln & 7) << 4);
      ah[mt] = *reinterpret_cast<const bf16x8*>((const char*)xh + byte);
      al[mt] = *reinterpret_cast<const bf16x8*>((const char*)xl + byte);
    }
    #pragma unroll
    for (int nt = 0; nt < 6; ++nt){
      int o = wstart + nt*16 + ln;
      const unsigned short* wp = w2 + (size_t)o*128 + kk*32 + g*8;
      bf16x8 whf = *reinterpret_cast<const bf16x8*>(wp);
      bf16x8 wlf = *reinterpret_cast<const bf16x8*>(wp + 49152);
      #pragma unroll
      for (int mt = 0; mt < 4; ++mt){
        acc[nt][mt] = __builtin_amdgcn_mfma_f32_16x16x32_bf16(ah[mt], whf, acc[nt][mt], 0, 0, 0);
        acc[nt][mt] = __builtin_amdgcn_mfma_f32_16x16x32_bf16(al[mt], whf, acc[nt][mt], 0, 0, 0);
        acc[nt][mt] = __builtin_amdgcn_mfma_f32_16x16x32_bf16(ah[mt], wlf, acc[nt][mt], 0, 0, 0);
      }
    }
  }
  // epilogue: relu on v, bf16, scatter (16 consecutive lanes = 32B contiguous)
  unsigned int ptab[16];
  #pragma unroll
  for (int mt = 0; mt < 4; ++mt)
    #pragma unroll
    for (int r = 0; r < 4; ++r)
      ptab[mt*4+r] = posTab[mt*16 + g*4 + r];
  #pragma unroll
  for (int nt = 0; nt < 6; ++nt){
    int o = wstart + nt*16 + ln;
    bool isv = (o >= 256);
    int oo = o & 127;
    unsigned short* dst = ((o < 128) ? qg : (o < 256 ? kg : vg)) + (oo >> 5)*10976 + (oo & 31);
    #pragma unroll
    for (int mt = 0; mt < 4; ++mt){
      #pragma unroll
      for (int r = 0; r < 4; ++r){
        float v = acc[nt][mt][r];
        if (isv) v = fmaxf(v, 0.f);
        dst[ptab[mt*4+r]] = f2b(v);
      }
    }
  }
}

// K3 (MFMA): attention per (window, head) on mfma_f32_16x16x32_bf16.
__global__ __launch_bounds__(256) void k3_attn(const unsigned short* __restrict__ qg,
        const unsigned short* __restrict__ kg, const unsigned short* __restrict__ vg,
        unsigned short* __restrict__ xatt){
  __shared__ __align__(16) unsigned short klds[352*32];    // [m][d]     22528 B
  __shared__ __align__(16) unsigned short vper[32*360];    // [d][m']    23040 B
  __shared__ __align__(16) unsigned short pbuf[4][640];    // per-wave [16][40]
  int bh = blockIdx.x;
  int bw = bh >> 2, h = bh & 3;
  int t = threadIdx.x;
  int wid = t >> 6, lane = t & 63;
  int g = lane >> 4, ln = lane & 15;
  const unsigned short* kbase = kg + (size_t)bh*LW*32;
  const unsigned short* vbase = vg + (size_t)bh*LW*32;
  const unsigned short* qbase = qg + (size_t)bh*LW*32;
  // stage K: straight uint4 copy, zero pad rows 343..351
  {
    const uint4* src = reinterpret_cast<const uint4*>(kbase);
    uint4* dst = reinterpret_cast<uint4*>(klds);
    for (int i = t; i < 1372; i += 256) dst[i] = src[i];
    for (int i = t; i < 288; i += 256) klds[10976 + i] = 0;
  }
  // stage V transposed + 32-key interleave: m -> (c = m>>5, pk = 2*(m&15) | ((m>>4)&1))
  for (int idx = t; idx < 10976; idx += 256){
    int m = idx >> 5, d = idx & 31;
    int km = m & 31;
    int pk = ((km & 15) << 1) | (km >> 4);
    vper[d*360 + ((m >> 5) << 5) + pk] = vbase[idx];
  }
  for (int i = t; i < 288; i += 256){       // zero V pad rows 343..351
    int m = 343 + (i >> 5), d = i & 31;
    int km = m & 31;
    int pk = ((km & 15) << 1) | (km >> 4);
    vper[d*360 + 320 + pk] = 0;
  }
  __syncthreads();
  int w1 = (bw>>4)&3, w2 = (bw>>2)&3, w3 = bw&3, b = bw>>6;
  unsigned short* pb = pbuf[wid];
  const f32x4 zero4 = {0.f, 0.f, 0.f, 0.f};
  for (int rt = wid; rt < 22; rt += 4){
    int row0 = rt << 4;
    bf16x8 qf = *reinterpret_cast<const bf16x8*>(qbase + (size_t)(row0 + ln)*32 + g*8);
    // QK^T: 22 n-tiles, single k-step (K=32=DH)
    f32x4 s[22];
    #pragma unroll
    for (int nt = 0; nt < 22; ++nt){
      bf16x8 kf = *reinterpret_cast<const bf16x8*>(&klds[(nt*16 + ln)*32 + g*8]);
      s[nt] = __builtin_amdgcn_mfma_f32_16x16x32_bf16(qf, kf, zero4, 0, 0, 0);
    }
    float mxs[4];
    #pragma unroll
    for (int q = 0; q < 4; ++q){
      float m0 = -1e30f;
      #pragma unroll
      for (int nt = 0; nt < 21; ++nt) m0 = fmaxf(m0, s[nt][q]);
      if (ln < 7) m0 = fmaxf(m0, s[21][q]);
      #pragma unroll
      for (int off = 8; off > 0; off >>= 1) m0 = fmaxf(m0, __shfl_xor(m0, off));
      mxs[q] = m0 * SCALE_;
    }
    f32x4 o0 = zero4, o1 = zero4;
    float sums[4] = {0.f, 0.f, 0.f, 0.f};
    #pragma unroll
    for (int c = 0; c < 11; ++c){
      #pragma unroll
      for (int q = 0; q < 4; ++q){
        float e0 = __expf(fmaf(s[2*c][q],   SCALE_, -mxs[q]));
        float e1 = (c*32 + 16 + ln < 343)
                 ? __expf(fmaf(s[2*c+1][q], SCALE_, -mxs[q])) : 0.f;
        sums[q] += e0 + e1;
        unsigned int pkd;
        asm volatile("v_cvt_pk_bf16_f32 %0, %1, %2" : "=v"(pkd) : "v"(e0), "v"(e1));
        *reinterpret_cast<unsigned int*>(&pb[(g*4+q)*40 + (ln<<1)]) = pkd;
      }
      asm volatile("s_waitcnt lgkmcnt(0)" ::: "memory");
      __builtin_amdgcn_sched_barrier(0);
      bf16x8 pa  = *reinterpret_cast<const bf16x8*>(&pb[ln*40 + g*8]);
      bf16x8 vb0 = *reinterpret_cast<const bf16x8*>(&vper[ln*360       + (c<<5) + g*8]);
      bf16x8 vb1 = *reinterpret_cast<const bf16x8*>(&vper[(16+ln)*360  + (c<<5) + g*8]);
      o0 = __builtin_amdgcn_mfma_f32_16x16x32_bf16(pa, vb0, o0, 0, 0, 0);
      o1 = __builtin_amdgcn_mfma_f32_16x16x32_bf16(pa, vb1, o1, 0, 0, 0);
    }
    float iss[4];
    #pragma unroll
    for (int q = 0; q < 4; ++q){
      float sq = sums[q];
      #pragma unroll
      for (int off = 8; off > 0; off >>= 1) sq += __shfl_xor(sq, off);
      iss[q] = 1.f / sq;
    }
    #pragma unroll
    for (int q = 0; q < 4; ++q){
      int l = row0 + g*4 + q;
      if (l < 343){
        int ss1 = l/49, ss2 = (l/7)%7, ss3 = l%7;
        int sp = (ss1*4+w1)*784 + (ss2*4+w2)*28 + (ss3*4+w3);
        size_t gaddr = ((size_t)b*SP + sp)*128 + h*32;
        xatt[gaddr + ln]      = f2b(o0[q]*iss[q]);
        xatt[gaddr + 16 + ln] = f2b(o1[q]*iss[q]);
      }
    }
  }
}

// K_wprep: w_cl [oc][ic][27] fp32 -> wbf bf16 slices [h][tap][kg][oc][8]
__global__ void k_wprep(const float* __restrict__ wcl, unsigned short* __restrict__ wbf){
  int f = blockIdx.x*256 + threadIdx.x;      // 442368 total
  int j  = f & 7;
  int oc = (f >> 3) & 127;
  int kgr= (f >> 10) & 7;
  int sl = f >> 13;                          // 0..53
  int h  = sl / 27, tap = sl % 27;
  int ic = h*64 + kgr*8 + j;
  wbf[f] = f2b(wcl[((size_t)oc*128 + ic)*27 + tap]);
}

// K6w: split proj weights into bf16 hi/lo pairs: w6[0..16384) hi, [16384..) lo
__global__ void k6w(const float* __restrict__ wproj, unsigned short* __restrict__ w6){
  int idx = blockIdx.x*256 + threadIdx.x;   // 16384 total
  float w = wproj[idx];
  unsigned short h = f2b(w);
  w6[idx] = h;
  w6[16384 + idx] = f2b(w - b2f(h));
}

// K4 v2: 3x3x3 conv as implicit GEMM on mfma_f32_16x16x32_bf16.
// Restructured: 128-thread blocks (2 waves), halo-only LDS (27648 B), weights
// streamed global->registers (wbf 432KB is L2-resident, broadcast across CUs)
// with one-tap-ahead double-buffered prefetch. NO per-tap barriers (only 2 per
// h-half for halo staging) — removes the vmcnt(0)-drain-per-tap that capped
// the old version at 22% MfmaUtil. Wave tile 64 pos x 64 oc: per (h,tap)
// 8 ds_read_b128 (A, conflict-free packing) + 8 coalesced global loads (B)
// feed 32 MFMAs. Fragment mappings/accumulation order identical to old k4.
__global__ __launch_bounds__(128) void k4_mfma(const unsigned short* __restrict__ xag,
        const unsigned short* __restrict__ wbf, unsigned short* __restrict__ yg){
  __shared__ __align__(16) unsigned short halo[8*216*8];   // 27648 B
  int t = threadIdx.x, wid = t >> 6, lane = t & 63;
  int g = lane >> 4, ln = lane & 15;
  int stile = blockIdx.x;
  int b = stile / 343, srem = stile % 343;
  int z0 = (srem/49)*4, y0 = ((srem/7)%7)*4, x0 = (srem%7)*4;
  int ohalf = wid;                       // which 64-oc half this wave owns
  int hp = (ln>>2)*6 + (ln&3);           // halo offset of row ln (m-tile adds mt*36)
  f32x4 acc[4][4] = {};                  // [nt][mt]
  // B-frag base: wbf idx (s,ks,nt) = s*8192 + ks*4096 + g*1024 + ohalf*512 + nt*128 + ln*8
  const unsigned short* wb0 = wbf + (size_t)(g*1024 + ohalf*512 + ln*8);
  bf16x8 b0[8], b1[8];

  #define BLOADX(dst_, s_) do { \
    const unsigned short* wp_ = wb0 + (size_t)(s_)*8192; \
    _Pragma("unroll") \
    for (int ks_ = 0; ks_ < 2; ++ks_) \
      _Pragma("unroll") \
      for (int nt_ = 0; nt_ < 4; ++nt_) \
        dst_[ks_*4+nt_] = *reinterpret_cast<const bf16x8*>(wp_ + ks_*4096 + nt_*128); \
  } while(0)

  #define COMPUTE(tap_, buf_) do { \
    int dz_ = (tap_)/9, r9_ = (tap_)%9, dy_ = r9_/3, dx_ = r9_%3; \
    int off_ = dz_*36 + dy_*6 + dx_; \
    bf16x8 af_[2][4]; \
    _Pragma("unroll") \
    for (int ks_ = 0; ks_ < 2; ++ks_) \
      _Pragma("unroll") \
      for (int mt_ = 0; mt_ < 4; ++mt_) \
        af_[ks_][mt_] = *reinterpret_cast<const bf16x8*>( \
            &halo[((ks_*4 + g)*216 + mt_*36 + hp + off_)*8]); \
    _Pragma("unroll") \
    for (int nt_ = 0; nt_ < 4; ++nt_) \
      _Pragma("unroll") \
      for (int ks_ = 0; ks_ < 2; ++ks_) \
        _Pragma("unroll") \
        for (int mt_ = 0; mt_ < 4; ++mt_) \
          acc[nt_][mt_] = __builtin_amdgcn_mfma_f32_16x16x32_bf16( \
              af_[ks_][mt_], buf_[ks_*4+nt_], acc[nt_][mt_], 0, 0, 0); \
  } while(0)

  int s = 0;
  BLOADX(b0, 0);
  for (int h = 0; h < 2; ++h){
    if (h) __syncthreads();              // all waves done reading h=0 halo
    for (int cidx = t; cidx < 1728; cidx += 128){
      int kgr = cidx / 216, pos = cidx % 216;
      int uz = pos / 36, r36 = pos % 36, uy = r36 / 6, ux = r36 % 6;
      int zz = z0 - 1 + uz, yy = y0 - 1 + uy, xx = x0 - 1 + ux;
      uint4 v = make_uint4(0u,0u,0u,0u);
      if (zz >= 0 && zz < 28 && yy >= 0 && yy < 28 && xx >= 0 && xx < 28)
        v = *reinterpret_cast<const uint4*>(
              &xag[(((size_t)b*SP) + zz*784 + yy*28 + xx)*128 + h*64 + kgr*8]);
      *reinterpret_cast<uint4*>(&halo[(size_t)cidx*8]) = v;
    }
    __syncthreads();
    for (int tp = 0; tp < 26; tp += 2){
      BLOADX(b1, s+1);
      COMPUTE(tp, b0);
      BLOADX(b0, s+2);
      COMPUTE(tp+1, b1);
      s += 2;
    }
    COMPUTE(26, b0);                     // tap 26 of this h
    ++s;                                 // s = 27 (after h=0) or 54
    if (s < 54) BLOADX(b0, s);           // prefetch (h=1, tap=0) across barrier
  }
  #pragma unroll
  for (int nt = 0; nt < 4; ++nt){
    int oc = ohalf*64 + nt*16 + ln;
    #pragma unroll
    for (int mt = 0; mt < 4; ++mt){
      #pragma unroll
      for (int r = 0; r < 4; ++r){
        int pos = (z0 + mt)*784 + (y0 + g)*28 + (x0 + r);
        yg[((size_t)b*SP + pos)*128 + oc] = f2b(acc[nt][mt][r]);
      }
    }
  }
  #undef BLOADX
  #undef COMPUTE
}

// K5 v2: per-channel sum/sumsq of y, uint4 loads (8 ch per thread), shfl +
// LDS-atomic reduction. Old version did 128 scalar 2B loads per thread.
__global__ __launch_bounds__(256) void k5_ystats(const unsigned short* __restrict__ yg,
                                                 float* __restrict__ misc){
  int t = threadIdx.x;
  int c8 = t & 15;          // channel group: channels c8*8 .. c8*8+7
  int pr = t >> 4;          // position row 0..15
  float s[8] = {0,0,0,0,0,0,0,0}, q[8] = {0,0,0,0,0,0,0,0};
  size_t base = (size_t)blockIdx.x * 256;   // 256 positions per block, grid 343
  for (int i = 0; i < 16; ++i){
    size_t pos = base + i*16 + pr;
    uint4 v = *reinterpret_cast<const uint4*>(yg + pos*128 + c8*8);
    #pragma unroll
    for (int j = 0; j < 4; ++j){
      unsigned int u = (&v.x)[j];
      float f0 = __uint_as_float(u << 16);
      float f1 = __uint_as_float(u & 0xffff0000u);
      s[2*j]   += f0; q[2*j]   += f0*f0;
      s[2*j+1] += f1; q[2*j+1] += f1*f1;
    }
  }
  #pragma unroll
  for (int j = 0; j < 8; ++j){
    s[j] += __shfl_xor(s[j], 16); q[j] += __shfl_xor(q[j], 16);
    s[j] += __shfl_xor(s[j], 32); q[j] += __shfl_xor(q[j], 32);
  }
  __shared__ float rs[128], rq[128];
  if (t < 128){ rs[t] = 0.f; rq[t] = 0.f; }
  __syncthreads();
  if ((t & 48) == 0){   // lanes 0..15 of each wave hold the wave partials
    #pragma unroll
    for (int j = 0; j < 8; ++j){
      atomicAdd(&rs[c8*8+j], s[j]);
      atomicAdd(&rq[c8*8+j], q[j]);
    }
  }
  __syncthreads();
  if (t < 128){
    atomicAdd(&misc[MISC_SUM + t], rs[t]);
    atomicAdd(&misc[MISC_SQ  + t], rq[t]);
  }
}

__global__ void k5b_finstats(const float* __restrict__ gcl, const float* __restrict__ bcl,
                             float* __restrict__ misc){
  int c = threadIdx.x;
  float mean = misc[MISC_SUM+c] / (float)PT;
  float var  = misc[MISC_SQ +c] / (float)PT - mean*mean;
  float a = gcl[c] * rsqrtf(var + EPS_);
  misc[MISC_A2+c] = a;
  misc[MISC_B2+c] = bcl[c] - mean*a;
}

// K6 (MFMA): out = shortcut + Wproj @ (x_att + silu(bn(y))) with split-bf16
// fp32 emulation (wh*bh + wl*bh + wh*bl).
__global__ __launch_bounds__(256) void k6_final(const unsigned short* __restrict__ xag,
        const unsigned short* __restrict__ yg, const unsigned short* __restrict__ w6,
        const float* __restrict__ xin, const float* __restrict__ misc,
        float* __restrict__ out){
  __shared__ __align__(16) unsigned short xh[8192];   // 16KB
  __shared__ __align__(16) unsigned short xl[8192];   // 16KB
  __shared__ float a2s[128], b2s[128];
  int t = threadIdx.x;
  int P0 = blockIdx.x * 64;
  int b = P0 / SP, sp0 = P0 % SP;
  if (t < 128){ a2s[t] = misc[MISC_A2+t]; b2s[t] = misc[MISC_B2+t]; }
  __syncthreads();
  // stage: v = xatt + silu(bn(y)) -> bf16 hi/lo, swizzled [pos][c]
  for (int idx = t; idx < 1024; idx += 256){
    int p = idx >> 4, c0 = (idx & 15) * 8;
    size_t gb = (size_t)(P0 + p)*128 + c0;
    uint4 yv4 = *reinterpret_cast<const uint4*>(yg + gb);
    uint4 xa4 = *reinterpret_cast<const uint4*>(xag + gb);
    unsigned int ph[4], pl[4];
    #pragma unroll
    for (int j = 0; j < 4; ++j){
      unsigned int uy = (&yv4.x)[j], ux = (&xa4.x)[j];
      int c = c0 + 2*j;
      float y0 = __uint_as_float(uy << 16)          * a2s[c]   + b2s[c];
      float y1 = __uint_as_float(uy & 0xffff0000u)  * a2s[c+1] + b2s[c+1];
      float v0 = __uint_as_float(ux << 16)         + y0 / (1.f + __expf(-y0));
      float v1 = __uint_as_float(ux & 0xffff0000u) + y1 / (1.f + __expf(-y1));
      unsigned short h0 = f2b(v0), h1 = f2b(v1);
      unsigned short l0 = f2b(v0 - b2f(h0)), l1 = f2b(v1 - b2f(h1));
      ph[j] = (unsigned int)h0 | ((unsigned int)h1 << 16);
      pl[j] = (unsigned int)l0 | ((unsigned int)l1 << 16);
    }
    int byte = (p*256 + c0*2) ^ ((p & 7) << 4);
    *reinterpret_cast<uint4*>((char*)xh + byte) = make_uint4(ph[0],ph[1],ph[2],ph[3]);
    *reinterpret_cast<uint4*>((char*)xl + byte) = make_uint4(pl[0],pl[1],pl[2],pl[3]);
  }
  __syncthreads();
  int wid = t >> 6, lane = t & 63;
  int g = lane >> 4, ln = lane & 15;
  f32x4 acc[2][4] = {};    // [o-tile][pos-tile]
  #pragma unroll 1
  for (int kk = 0; kk < 4; ++kk){
    bf16x8 bh[4], bl[4];
    #pragma unroll
    for (int pt = 0; pt < 4; ++pt){
      int row = pt*16 + ln;
      int byte = (row*256 + kk*64 + g*16) ^ ((ln & 7) << 4);
      bh[pt] = *reinterpret_cast<const bf16x8*>((const char*)xh + byte);
      bl[pt] = *reinterpret_cast<const bf16x8*>((const char*)xl + byte);
    }
    #pragma unroll
    for (int ot = 0; ot < 2; ++ot){
      int o = wid*32 + ot*16 + ln;
      const unsigned short* wp = w6 + (size_t)o*128 + kk*32 + g*8;
      bf16x8 wh = *reinterpret_cast<const bf16x8*>(wp);
      bf16x8 wl = *reinterpret_cast<const bf16x8*>(wp + 16384);
      #pragma unroll
      for (int pt = 0; pt < 4; ++pt){
        acc[ot][pt] = __builtin_amdgcn_mfma_f32_16x16x32_bf16(wh, bh[pt], acc[ot][pt], 0, 0, 0);
        acc[ot][pt] = __builtin_amdgcn_mfma_f32_16x16x32_bf16(wl, bh[pt], acc[ot][pt], 0, 0, 0);
        acc[ot][pt] = __builtin_amdgcn_mfma_f32_16x16x32_bf16(wh, bl[pt], acc[ot][pt], 0, 0, 0);
      }
    }
  }
  #pragma unroll
  for (int ot = 0; ot < 2; ++ot){
    #pragma unroll
    for (int r = 0; r < 4; ++r){
      int o = wid*32 + ot*16 + g*4 + r;
      size_t gbase = ((size_t)b*128 + o)*SP + sp0;
      #pragma unroll
      for (int pt = 0; pt < 4; ++pt){
        size_t gaddr = gbase + pt*16 + ln;
        out[gaddr] = xin[gaddr] + acc[ot][pt][r];
      }
    }
  }
}

extern "C" void kernel_launch(void* const* d_in, const int* in_sizes, int n_in,
                              void* d_out, int out_size, void* d_ws, size_t ws_size,
                              hipStream_t stream){
  const float* x      = (const float*)d_in[0];
  const float* g_in   = (const float*)d_in[1];
  const float* b_in   = (const float*)d_in[2];
  const float* w_qk   = (const float*)d_in[3];
  const float* w_v    = (const float*)d_in[4];
  const float* w_cl   = (const float*)d_in[5];
  const float* g_cl   = (const float*)d_in[6];
  const float* b_cl   = (const float*)d_in[7];
  const float* w_proj = (const float*)d_in[8];
  float* out = (float*)d_out;

  char* ws = (char*)d_ws;
  unsigned short* qg  = (unsigned short*)ws;
  unsigned short* kgp = qg  + 11239424;
  unsigned short* vg  = kgp + 11239424;
  unsigned short* xag = vg  + 11239424;
  unsigned short* yg  = xag + 11239424;
  float* misc = (float*)(ws + (size_t)5*22478848);   // 112,394,240 B offset
  unsigned short* wbf = qg;            // reuses qg region AFTER k3 consumed q
  unsigned short* w6  = qg + 524288;   // proj hi/lo weights, past wbf's 442368
  unsigned short* w2  = yg;            // qkv hi/lo weights; yg free until k4

  hipMemsetAsync(misc + MISC_SUM, 0, 768*sizeof(float), stream);
  k0_partial  <<<1024, 256, 0, stream>>>(x, misc);
  k1_bias     <<<3, 128, 0, stream>>>(w_qk, w_v, g_in, b_in, misc);
  k1w         <<<192, 256, 0, stream>>>(w_qk, w_v, w2);
  k2_qkv      <<<1372, 256, 0, stream>>>(x, w2, misc, qg, kgp, vg);
  k3_attn     <<<1024, 256, 0, stream>>>(qg, kgp, vg, xag);
  k_wprep     <<<1728, 256, 0, stream>>>(w_cl, wbf);
  k6w         <<<64, 256, 0, stream>>>(w_proj, w6);
  k4_mfma     <<<1372, 128, 0, stream>>>(xag, wbf, yg);
  k5_ystats   <<<343, 256, 0, stream>>>(yg, misc);
  k5b_finstats<<<1, 128, 0, stream>>>(g_cl, b_cl, misc);
  k6_final    <<<1372, 256, 0, stream>>>(xag, yg, w6, x, misc, out);
}